// Round 1
// baseline (797.139 us; speedup 1.0000x reference)
//
#include <hip/hip_runtime.h>
#include <hip/hip_bf16.h>

// ---------------------------------------------------------------------------
// DecoderBlock: proj -> banded MHA -> LN+residual -> 3x conv1d(softplus) -> LN
// S=2048, L=5S=10240, DIM=512, HEADS=4, hd=128, KDIM=136 (pad->160), EXT=64
// All GEMMs in bf16 MFMA (16x16x32), fp32 accum. Threshold is bf16-scale.
// ---------------------------------------------------------------------------

#define S_LEN   2048
#define L_LEN   10240
#define DIM     512
#define KDIM    136
#define KDIM_P  160      // padded to multiple of 32
#define NPOS    8
#define HEADS   4
#define HDIM    128
#define NLAYERS 3
#define CONV_K  1536     // 3*DIM

typedef __attribute__((ext_vector_type(8))) short bf16x8;
typedef __attribute__((ext_vector_type(4))) float f32x4;

__device__ __forceinline__ float softplus_f(float x) {
    return x > 20.0f ? x : log1pf(__expf(x));
}

// ---------------------------------------------------------------------------
// Generic GEMM: C[m,n] = act( sum_k A[m*lda+k] * W[n*ldw+k] + bias[n] )
// A,W bf16 row-major. Wave computes 16(m) x 64(n). Block = 4 waves = 64x64.
// Requires M%64==0, N%64==0, K%32==0.
// ---------------------------------------------------------------------------
template<bool SOFTPLUS, bool OUT_BF16>
__global__ __launch_bounds__(256) void gemm_bt(
    const __hip_bfloat16* __restrict__ A, int lda,
    const __hip_bfloat16* __restrict__ W, int ldw,
    const float* __restrict__ bias,
    __hip_bfloat16* __restrict__ Cb, float* __restrict__ Cf, int ldc,
    int K)
{
    const int lane = threadIdx.x & 63;
    const int wave = threadIdx.x >> 6;
    const int m0 = blockIdx.x * 64 + wave * 16;
    const int n0 = blockIdx.y * 64;
    const int r16 = lane & 15;
    const int quad = lane >> 4;

    const __hip_bfloat16* Ap = A + (size_t)(m0 + r16) * lda + quad * 8;
    const __hip_bfloat16* Wp = W + (size_t)(n0 + r16) * ldw + quad * 8;

    f32x4 acc0 = {0.f, 0.f, 0.f, 0.f};
    f32x4 acc1 = {0.f, 0.f, 0.f, 0.f};
    f32x4 acc2 = {0.f, 0.f, 0.f, 0.f};
    f32x4 acc3 = {0.f, 0.f, 0.f, 0.f};

    for (int k = 0; k < K; k += 32) {
        bf16x8 a = *(const bf16x8*)(Ap + k);
        bf16x8 b0 = *(const bf16x8*)(Wp + k);
        bf16x8 b1 = *(const bf16x8*)(Wp + (size_t)16 * ldw + k);
        bf16x8 b2 = *(const bf16x8*)(Wp + (size_t)32 * ldw + k);
        bf16x8 b3 = *(const bf16x8*)(Wp + (size_t)48 * ldw + k);
        acc0 = __builtin_amdgcn_mfma_f32_16x16x32_bf16(a, b0, acc0, 0, 0, 0);
        acc1 = __builtin_amdgcn_mfma_f32_16x16x32_bf16(a, b1, acc1, 0, 0, 0);
        acc2 = __builtin_amdgcn_mfma_f32_16x16x32_bf16(a, b2, acc2, 0, 0, 0);
        acc3 = __builtin_amdgcn_mfma_f32_16x16x32_bf16(a, b3, acc3, 0, 0, 0);
    }

    f32x4 accs[4] = {acc0, acc1, acc2, acc3};
    #pragma unroll
    for (int j = 0; j < 4; ++j) {
        const int col = n0 + j * 16 + r16;
        const float bs = bias[col - n0 + n0];  // bias indexed by global n
        #pragma unroll
        for (int r = 0; r < 4; ++r) {
            const int row = m0 + quad * 4 + r;
            float v = accs[j][r] + bs;
            if (SOFTPLUS) v = softplus_f(v);
            if (OUT_BF16) Cb[(size_t)row * ldc + col] = __float2bfloat16(v);
            else          Cf[(size_t)row * ldc + col] = v;
        }
    }
}

// ---------------------------------------------------------------------------
// Banded attention, online softmax. One block per query l; wave = head.
// Lane handles dims (2*lane, 2*lane+1) of the 128-dim head.
// ---------------------------------------------------------------------------
__global__ __launch_bounds__(256) void attn_kernel(
    const __hip_bfloat16* __restrict__ qb,   // [L, 512]
    const __hip_bfloat16* __restrict__ kb,   // [S, 512]
    const __hip_bfloat16* __restrict__ vb,   // [S, 512]
    __hip_bfloat16* __restrict__ ob)         // [L, 512]
{
    const int l = blockIdx.x;
    const int h = threadIdx.x >> 6;
    const int lane = threadIdx.x & 63;
    const int d = h * HDIM + lane * 2;

    const float q0 = __bfloat162float(qb[(size_t)l * DIM + d]);
    const float q1 = __bfloat162float(qb[(size_t)l * DIM + d + 1]);

    int i_lo = (l > 68) ? (l - 64) / 5 : 0;          // ceil((l-68)/5)
    int i_hi = (l + 64) / 5;
    if (i_hi > S_LEN - 1) i_hi = S_LEN - 1;

    float m = -1e30f, dsum = 0.f, o0 = 0.f, o1 = 0.f;
    for (int i = i_lo; i <= i_hi; ++i) {
        const size_t off = (size_t)i * DIM + d;
        float p = q0 * __bfloat162float(kb[off]) + q1 * __bfloat162float(kb[off + 1]);
        #pragma unroll
        for (int o = 32; o; o >>= 1) p += __shfl_xor(p, o);
        const float s = p * 0.08838834764831845f;   // 1/sqrt(128)
        const float mn = fmaxf(m, s);
        const float scale = __expf(m - mn);
        const float w = __expf(s - mn);
        o0 = o0 * scale + w * __bfloat162float(vb[off]);
        o1 = o1 * scale + w * __bfloat162float(vb[off + 1]);
        dsum = dsum * scale + w;
        m = mn;
    }
    const float inv = 1.0f / dsum;
    ob[(size_t)l * DIM + d]     = __float2bfloat16(o0 * inv);
    ob[(size_t)l * DIM + d + 1] = __float2bfloat16(o1 * inv);
}

// ---------------------------------------------------------------------------
// LayerNorm(attn_out) + residual -> bf16 into padded conv buffer (row r+1)
// ---------------------------------------------------------------------------
__global__ __launch_bounds__(256) void ln_residual_kernel(
    const float* __restrict__ attn_out, const float* __restrict__ residual,
    __hip_bfloat16* __restrict__ hp0)
{
    __shared__ float red[4];
    const int r = blockIdx.x;
    const int t = threadIdx.x;
    const size_t base = (size_t)r * DIM + t * 2;
    float z0 = attn_out[base], z1 = attn_out[base + 1];

    float s = z0 + z1;
    #pragma unroll
    for (int o = 32; o; o >>= 1) s += __shfl_xor(s, o);
    if ((t & 63) == 0) red[t >> 6] = s;
    __syncthreads();
    const float mean = (red[0] + red[1] + red[2] + red[3]) * (1.0f / DIM);
    __syncthreads();

    const float d0 = z0 - mean, d1 = z1 - mean;
    float vq = d0 * d0 + d1 * d1;
    #pragma unroll
    for (int o = 32; o; o >>= 1) vq += __shfl_xor(vq, o);
    if ((t & 63) == 0) red[t >> 6] = vq;
    __syncthreads();
    const float var = (red[0] + red[1] + red[2] + red[3]) * (1.0f / DIM);
    const float rstd = rsqrtf(var + 1e-5f);

    const float y0 = d0 * rstd + residual[base];
    const float y1 = d1 * rstd + residual[base + 1];
    __hip_bfloat16* out = hp0 + (size_t)(r + 1) * DIM + t * 2;
    out[0] = __float2bfloat16(y0);
    out[1] = __float2bfloat16(y1);
}

// ---------------------------------------------------------------------------
// Final: LayerNorm(conv_out + skip_out) -> d_out (f32)
// ---------------------------------------------------------------------------
__global__ __launch_bounds__(256) void final_ln_kernel(
    const float* __restrict__ conv_out, const float* __restrict__ skip_out,
    float* __restrict__ out)
{
    __shared__ float red[4];
    const int r = blockIdx.x;
    const int t = threadIdx.x;
    const size_t base = (size_t)r * DIM + t * 2;
    float z0 = conv_out[base] + skip_out[base];
    float z1 = conv_out[base + 1] + skip_out[base + 1];

    float s = z0 + z1;
    #pragma unroll
    for (int o = 32; o; o >>= 1) s += __shfl_xor(s, o);
    if ((t & 63) == 0) red[t >> 6] = s;
    __syncthreads();
    const float mean = (red[0] + red[1] + red[2] + red[3]) * (1.0f / DIM);
    __syncthreads();

    const float d0 = z0 - mean, d1 = z1 - mean;
    float vq = d0 * d0 + d1 * d1;
    #pragma unroll
    for (int o = 32; o; o >>= 1) vq += __shfl_xor(vq, o);
    if ((t & 63) == 0) red[t >> 6] = vq;
    __syncthreads();
    const float var = (red[0] + red[1] + red[2] + red[3]) * (1.0f / DIM);
    const float rstd = rsqrtf(var + 1e-5f);

    out[base]     = d0 * rstd;
    out[base + 1] = d1 * rstd;
}

// ---------------------------------------------------------------------------
// Staging kernels
// ---------------------------------------------------------------------------
__global__ void build_src_kernel(const float* __restrict__ x,
                                 __hip_bfloat16* __restrict__ src)
{
    int idx = blockIdx.x * 256 + threadIdx.x;   // over S*KDIM_P
    if (idx >= S_LEN * KDIM_P) return;
    int i = idx / KDIM_P, j = idx % KDIM_P;
    float v;
    if (j < 128)       v = x[i * 128 + j];
    else if (j < KDIM) { int e = j - 128; v = (float)(i & ((2 << e) - 1)) / (float)(1 << e); }
    else               v = 0.f;
    src[idx] = __float2bfloat16(v);
}

__global__ void convert_pad_kernel(const float* __restrict__ src,
                                   __hip_bfloat16* __restrict__ dst,
                                   int R, int C, int Cp)
{
    int idx = blockIdx.x * 256 + threadIdx.x;
    if (idx >= R * Cp) return;
    int r = idx / Cp, c = idx % Cp;
    dst[idx] = __float2bfloat16(c < C ? src[(size_t)r * C + c] : 0.f);
}

// conv_w [3][512][512][3] -> wt [3][512][3*512] as [c][k][ci]
__global__ void conv_wt_kernel(const float* __restrict__ w,
                               __hip_bfloat16* __restrict__ wt)
{
    int idx = blockIdx.x * 256 + threadIdx.x;   // over 3*512*1536
    if (idx >= NLAYERS * DIM * CONV_K) return;
    int lc = idx / CONV_K;          // li*512 + c
    int rem = idx % CONV_K;
    int k = rem / DIM, ci = rem % DIM;
    wt[idx] = __float2bfloat16(w[(size_t)lc * CONV_K + ci * 3 + k]);
}

__global__ void zero_pad_rows_kernel(__hip_bfloat16* hp0, __hip_bfloat16* hp1)
{
    const int t = threadIdx.x;  // 512
    const __hip_bfloat16 z = __float2bfloat16(0.f);
    if      (blockIdx.x == 0) hp0[t] = z;
    else if (blockIdx.x == 1) hp0[(size_t)(L_LEN + 1) * DIM + t] = z;
    else if (blockIdx.x == 2) hp1[t] = z;
    else                      hp1[(size_t)(L_LEN + 1) * DIM + t] = z;
}

// ---------------------------------------------------------------------------
extern "C" void kernel_launch(void* const* d_in, const int* in_sizes, int n_in,
                              void* d_out, int out_size, void* d_ws, size_t ws_size,
                              hipStream_t stream)
{
    const float* x        = (const float*)d_in[0];
    const float* residual = (const float*)d_in[1];
    const float* proj_w   = (const float*)d_in[2];
    const float* proj_b   = (const float*)d_in[3];
    const float* q_w      = (const float*)d_in[4];
    const float* k_w      = (const float*)d_in[5];
    const float* v_w      = (const float*)d_in[6];
    const float* in_b     = (const float*)d_in[7];
    const float* out_w    = (const float*)d_in[8];
    const float* out_b    = (const float*)d_in[9];
    const float* conv_w   = (const float*)d_in[10];
    const float* conv_b   = (const float*)d_in[11];
    const float* skip_w   = (const float*)d_in[12];
    const float* skip_b   = (const float*)d_in[13];
    float* out = (float*)d_out;

    // workspace layout (all offsets 256B-aligned)
    char* ws = (char*)d_ws;
    size_t off = 0;
    auto alloc = [&](size_t bytes) { char* p = ws + off; off += (bytes + 255) & ~(size_t)255; return p; };

    __hip_bfloat16* src_b   = (__hip_bfloat16*)alloc((size_t)S_LEN * KDIM_P * 2);
    __hip_bfloat16* projw_b = (__hip_bfloat16*)alloc((size_t)DIM * 5 * KDIM_P * 2);
    __hip_bfloat16* qw_b    = (__hip_bfloat16*)alloc((size_t)DIM * DIM * 2);
    __hip_bfloat16* kw_b    = (__hip_bfloat16*)alloc((size_t)DIM * KDIM_P * 2);
    __hip_bfloat16* vw_b    = (__hip_bfloat16*)alloc((size_t)DIM * KDIM_P * 2);
    __hip_bfloat16* outw_b  = (__hip_bfloat16*)alloc((size_t)DIM * DIM * 2);
    __hip_bfloat16* skipw_b = (__hip_bfloat16*)alloc((size_t)DIM * DIM * 2);
    __hip_bfloat16* convwt  = (__hip_bfloat16*)alloc((size_t)NLAYERS * DIM * CONV_K * 2);
    __hip_bfloat16* tgt_b   = (__hip_bfloat16*)alloc((size_t)L_LEN * DIM * 2);
    __hip_bfloat16* q_b     = (__hip_bfloat16*)alloc((size_t)L_LEN * DIM * 2);
    __hip_bfloat16* k_b     = (__hip_bfloat16*)alloc((size_t)S_LEN * DIM * 2);
    __hip_bfloat16* v_b     = (__hip_bfloat16*)alloc((size_t)S_LEN * DIM * 2);
    __hip_bfloat16* o_b     = (__hip_bfloat16*)alloc((size_t)L_LEN * DIM * 2);
    float*          attn_f  = (float*)alloc((size_t)L_LEN * DIM * 4);   // reused as skip_out
    __hip_bfloat16* hp0     = (__hip_bfloat16*)alloc((size_t)(L_LEN + 2) * DIM * 2);
    __hip_bfloat16* hp1     = (__hip_bfloat16*)alloc((size_t)(L_LEN + 2) * DIM * 2);
    float*          conv_f  = (float*)alloc((size_t)L_LEN * DIM * 4);
    float*          skip_f  = attn_f;  // alias: attn_out dead after LN
    (void)ws_size; (void)n_in; (void)in_sizes; (void)out_size;

    // --- staging ---
    build_src_kernel<<<(S_LEN * KDIM_P + 255) / 256, 256, 0, stream>>>(x, src_b);
    convert_pad_kernel<<<(DIM * 5 * KDIM_P + 255) / 256, 256, 0, stream>>>(proj_w, projw_b, DIM * 5, KDIM, KDIM_P);
    convert_pad_kernel<<<(DIM * DIM + 255) / 256, 256, 0, stream>>>(q_w, qw_b, DIM, DIM, DIM);
    convert_pad_kernel<<<(DIM * KDIM_P + 255) / 256, 256, 0, stream>>>(k_w, kw_b, DIM, KDIM, KDIM_P);
    convert_pad_kernel<<<(DIM * KDIM_P + 255) / 256, 256, 0, stream>>>(v_w, vw_b, DIM, KDIM, KDIM_P);
    convert_pad_kernel<<<(DIM * DIM + 255) / 256, 256, 0, stream>>>(out_w, outw_b, DIM, DIM, DIM);
    convert_pad_kernel<<<(DIM * DIM + 255) / 256, 256, 0, stream>>>(skip_w, skipw_b, DIM, DIM, DIM);
    conv_wt_kernel<<<(NLAYERS * DIM * CONV_K + 255) / 256, 256, 0, stream>>>(conv_w, convwt);
    zero_pad_rows_kernel<<<4, 512, 0, stream>>>(hp0, hp1);

    // --- proj: [2048,160] x [2560,160] -> tgt flat = [10240,512] ---
    gemm_bt<false, true><<<dim3(S_LEN / 64, DIM * 5 / 64), 256, 0, stream>>>(
        src_b, KDIM_P, projw_b, KDIM_P, proj_b, tgt_b, nullptr, DIM * 5, KDIM_P);
    // --- q = tgt @ q_w.T + in_b[0:512] ---
    gemm_bt<false, true><<<dim3(L_LEN / 64, DIM / 64), 256, 0, stream>>>(
        tgt_b, DIM, qw_b, DIM, in_b, q_b, nullptr, DIM, DIM);
    // --- k, v ---
    gemm_bt<false, true><<<dim3(S_LEN / 64, DIM / 64), 256, 0, stream>>>(
        src_b, KDIM_P, kw_b, KDIM_P, in_b + DIM, k_b, nullptr, DIM, KDIM_P);
    gemm_bt<false, true><<<dim3(S_LEN / 64, DIM / 64), 256, 0, stream>>>(
        src_b, KDIM_P, vw_b, KDIM_P, in_b + 2 * DIM, v_b, nullptr, DIM, KDIM_P);

    // --- banded attention ---
    attn_kernel<<<L_LEN, 256, 0, stream>>>(q_b, k_b, v_b, o_b);

    // --- out proj -> f32 ---
    gemm_bt<false, false><<<dim3(L_LEN / 64, DIM / 64), 256, 0, stream>>>(
        o_b, DIM, outw_b, DIM, out_b, nullptr, attn_f, DIM, DIM);

    // --- LN + residual -> hp0 rows 1..L (bf16) ---
    ln_residual_kernel<<<L_LEN, 256, 0, stream>>>(attn_f, residual, hp0);

    // --- skip GEMM (reads cnn_input bf16 = hp0+512) -> skip_f (aliases attn_f) ---
    gemm_bt<false, false><<<dim3(L_LEN / 64, DIM / 64), 256, 0, stream>>>(
        hp0 + DIM, DIM, skipw_b, DIM, skip_b, nullptr, skip_f, DIM, DIM);

    // --- conv stack: sliding-window GEMMs, K=1536, lda=512 ---
    gemm_bt<true, true><<<dim3(L_LEN / 64, DIM / 64), 256, 0, stream>>>(
        hp0, DIM, convwt, CONV_K, conv_b, hp1 + DIM, nullptr, DIM, CONV_K);
    gemm_bt<true, true><<<dim3(L_LEN / 64, DIM / 64), 256, 0, stream>>>(
        hp1, DIM, convwt + (size_t)DIM * CONV_K, CONV_K, conv_b + DIM, hp0 + DIM, nullptr, DIM, CONV_K);
    gemm_bt<true, false><<<dim3(L_LEN / 64, DIM / 64), 256, 0, stream>>>(
        hp0, DIM, convwt + (size_t)2 * DIM * CONV_K, CONV_K, conv_b + 2 * DIM, nullptr, conv_f, DIM, CONV_K);

    // --- final LN ---
    final_ln_kernel<<<L_LEN, 256, 0, stream>>>(conv_f, skip_f, out);
}

// Round 2
// 482.314 us; speedup vs baseline: 1.6527x; 1.6527x over previous
//
#include <hip/hip_runtime.h>
#include <hip/hip_bf16.h>

// ---------------------------------------------------------------------------
// DecoderBlock: proj -> banded MHA -> LN+residual -> 3x conv1d(softplus) -> LN
// S=2048, L=5S=10240, DIM=512, HEADS=4, hd=128, KDIM=136 (pad->160), EXT=64
// GEMMs: m97-style 128x128 tile, LDS staging via global_load_lds(16B),
// mfma_f32_16x16x32_bf16, fp32 accum.
// ---------------------------------------------------------------------------

#define S_LEN   2048
#define L_LEN   10240
#define DIM     512
#define KDIM    136
#define KDIM_P  160      // padded to multiple of 32
#define NPOS    8
#define HEADS   4
#define HDIM    128
#define NLAYERS 3
#define CONV_K  1536     // 3*DIM

typedef __attribute__((ext_vector_type(8))) short bf16x8;
typedef __attribute__((ext_vector_type(4))) float f32x4;

__device__ __forceinline__ float softplus_f(float x) {
    return x > 20.0f ? x : log1pf(__expf(x));
}

__device__ __forceinline__ void gload_lds16(const __hip_bfloat16* g,
                                            __hip_bfloat16* l) {
    // async global->LDS DMA, 16B/lane; LDS dest = wave-uniform base + lane*16
    __builtin_amdgcn_global_load_lds(
        (const __attribute__((address_space(1))) void*)g,
        (__attribute__((address_space(3))) void*)l, 16, 0, 0);
}

// ---------------------------------------------------------------------------
// GEMM: C[m,n] = act( sum_k A[m*lda+k] * W[n*ldw+k] + bias[n] )
// Block = 128(m) x 128(n), 4 waves in 2x2, each wave 64x64 = 4x4 MFMA tiles.
// LDS: As/Bs [128][32] bf16 (8 KB each), contiguous (global_load_lds layout).
// Requires M%128==0, N%128==0, K%32==0, row strides 16B-aligned.
// ---------------------------------------------------------------------------
template<bool SOFTPLUS, bool OUT_BF16>
__global__ __launch_bounds__(256) void gemm128(
    const __hip_bfloat16* __restrict__ A, int lda,
    const __hip_bfloat16* __restrict__ W, int ldw,
    const float* __restrict__ bias,
    __hip_bfloat16* __restrict__ Cb, float* __restrict__ Cf, int ldc,
    int K)
{
    __shared__ __hip_bfloat16 As[128 * 32];
    __shared__ __hip_bfloat16 Bs[128 * 32];

    const int t = threadIdx.x;
    const int w = t >> 6;
    const int lane = t & 63;
    const int r16 = lane & 15;
    const int quad = lane >> 4;

    const int m0 = blockIdx.x * 128;
    const int n0 = blockIdx.y * 128;
    const int mo = (w >> 1) * 64;   // wave m-offset within tile
    const int no = (w & 1) * 64;    // wave n-offset within tile

    // staging: load i in {0,1}: linear = i*256+t; row = linear/4; col=(linear%4)*8
    const int srow = t >> 2;
    const int scol = (t & 3) * 8;
    const __hip_bfloat16* Ag0 = A + (size_t)(m0 + srow) * lda + scol;
    const __hip_bfloat16* Ag1 = A + (size_t)(m0 + 64 + srow) * lda + scol;
    const __hip_bfloat16* Wg0 = W + (size_t)(n0 + srow) * ldw + scol;
    const __hip_bfloat16* Wg1 = W + (size_t)(n0 + 64 + srow) * ldw + scol;
    // wave-uniform LDS bases (lane*16B appended by HW)
    __hip_bfloat16* lA0 = &As[(size_t)(w * 64) * 8];
    __hip_bfloat16* lA1 = &As[(size_t)(256 + w * 64) * 8];
    __hip_bfloat16* lB0 = &Bs[(size_t)(w * 64) * 8];
    __hip_bfloat16* lB1 = &Bs[(size_t)(256 + w * 64) * 8];

    f32x4 acc[4][4];
    #pragma unroll
    for (int i = 0; i < 4; ++i)
        #pragma unroll
        for (int j = 0; j < 4; ++j)
            acc[i][j] = (f32x4){0.f, 0.f, 0.f, 0.f};

    for (int k0 = 0; k0 < K; k0 += 32) {
        gload_lds16(Ag0 + k0, lA0);
        gload_lds16(Ag1 + k0, lA1);
        gload_lds16(Wg0 + k0, lB0);
        gload_lds16(Wg1 + k0, lB1);
        __syncthreads();

        bf16x8 af[4], bfr[4];
        #pragma unroll
        for (int i = 0; i < 4; ++i) {
            af[i]  = *(const bf16x8*)&As[(mo + i * 16 + r16) * 32 + quad * 8];
            bfr[i] = *(const bf16x8*)&Bs[(no + i * 16 + r16) * 32 + quad * 8];
        }
        #pragma unroll
        for (int i = 0; i < 4; ++i)
            #pragma unroll
            for (int j = 0; j < 4; ++j)
                acc[i][j] = __builtin_amdgcn_mfma_f32_16x16x32_bf16(
                    af[i], bfr[j], acc[i][j], 0, 0, 0);
        __syncthreads();
    }

    #pragma unroll
    for (int i = 0; i < 4; ++i) {
        const int row_base = m0 + mo + i * 16 + quad * 4;
        #pragma unroll
        for (int j = 0; j < 4; ++j) {
            const int col = n0 + no + j * 16 + r16;
            const float bs = bias[col];
            #pragma unroll
            for (int r = 0; r < 4; ++r) {
                float v = acc[i][j][r] + bs;
                if (SOFTPLUS) v = softplus_f(v);
                const size_t idx = (size_t)(row_base + r) * ldc + col;
                if (OUT_BF16) Cb[idx] = __float2bfloat16(v);
                else          Cf[idx] = v;
            }
        }
    }
}

// ---------------------------------------------------------------------------
// Banded attention, online softmax. One block per query l; wave = head.
// Lane handles dims (2*lane, 2*lane+1) of the 128-dim head.
// ---------------------------------------------------------------------------
__global__ __launch_bounds__(256) void attn_kernel(
    const __hip_bfloat16* __restrict__ qb,   // [L, 512]
    const __hip_bfloat16* __restrict__ kb,   // [S, 512]
    const __hip_bfloat16* __restrict__ vb,   // [S, 512]
    __hip_bfloat16* __restrict__ ob)         // [L, 512]
{
    const int l = blockIdx.x;
    const int h = threadIdx.x >> 6;
    const int lane = threadIdx.x & 63;
    const int d = h * HDIM + lane * 2;

    const float q0 = __bfloat162float(qb[(size_t)l * DIM + d]);
    const float q1 = __bfloat162float(qb[(size_t)l * DIM + d + 1]);

    int i_lo = (l > 68) ? (l - 64) / 5 : 0;
    int i_hi = (l + 64) / 5;
    if (i_hi > S_LEN - 1) i_hi = S_LEN - 1;

    float m = -1e30f, dsum = 0.f, o0 = 0.f, o1 = 0.f;
    for (int i = i_lo; i <= i_hi; ++i) {
        const size_t off = (size_t)i * DIM + d;
        float p = q0 * __bfloat162float(kb[off]) + q1 * __bfloat162float(kb[off + 1]);
        #pragma unroll
        for (int o = 32; o; o >>= 1) p += __shfl_xor(p, o);
        const float s = p * 0.08838834764831845f;   // 1/sqrt(128)
        const float mn = fmaxf(m, s);
        const float scale = __expf(m - mn);
        const float wgt = __expf(s - mn);
        o0 = o0 * scale + wgt * __bfloat162float(vb[off]);
        o1 = o1 * scale + wgt * __bfloat162float(vb[off + 1]);
        dsum = dsum * scale + wgt;
        m = mn;
    }
    const float inv = 1.0f / dsum;
    ob[(size_t)l * DIM + d]     = __float2bfloat16(o0 * inv);
    ob[(size_t)l * DIM + d + 1] = __float2bfloat16(o1 * inv);
}

// ---------------------------------------------------------------------------
// LayerNorm(attn_out) + residual -> bf16 into padded conv buffer (row r+1)
// ---------------------------------------------------------------------------
__global__ __launch_bounds__(256) void ln_residual_kernel(
    const float* __restrict__ attn_out, const float* __restrict__ residual,
    __hip_bfloat16* __restrict__ hp0)
{
    __shared__ float red[4];
    const int r = blockIdx.x;
    const int t = threadIdx.x;
    const size_t base = (size_t)r * DIM + t * 2;
    float z0 = attn_out[base], z1 = attn_out[base + 1];

    float s = z0 + z1;
    #pragma unroll
    for (int o = 32; o; o >>= 1) s += __shfl_xor(s, o);
    if ((t & 63) == 0) red[t >> 6] = s;
    __syncthreads();
    const float mean = (red[0] + red[1] + red[2] + red[3]) * (1.0f / DIM);
    __syncthreads();

    const float d0 = z0 - mean, d1 = z1 - mean;
    float vq = d0 * d0 + d1 * d1;
    #pragma unroll
    for (int o = 32; o; o >>= 1) vq += __shfl_xor(vq, o);
    if ((t & 63) == 0) red[t >> 6] = vq;
    __syncthreads();
    const float var = (red[0] + red[1] + red[2] + red[3]) * (1.0f / DIM);
    const float rstd = rsqrtf(var + 1e-5f);

    const float y0 = d0 * rstd + residual[base];
    const float y1 = d1 * rstd + residual[base + 1];
    __hip_bfloat16* out = hp0 + (size_t)(r + 1) * DIM + t * 2;
    out[0] = __float2bfloat16(y0);
    out[1] = __float2bfloat16(y1);
}

// ---------------------------------------------------------------------------
// Final: LayerNorm(conv_out + skip_out) -> d_out (f32)
// ---------------------------------------------------------------------------
__global__ __launch_bounds__(256) void final_ln_kernel(
    const float* __restrict__ conv_out, const float* __restrict__ skip_out,
    float* __restrict__ out)
{
    __shared__ float red[4];
    const int r = blockIdx.x;
    const int t = threadIdx.x;
    const size_t base = (size_t)r * DIM + t * 2;
    float z0 = conv_out[base] + skip_out[base];
    float z1 = conv_out[base + 1] + skip_out[base + 1];

    float s = z0 + z1;
    #pragma unroll
    for (int o = 32; o; o >>= 1) s += __shfl_xor(s, o);
    if ((t & 63) == 0) red[t >> 6] = s;
    __syncthreads();
    const float mean = (red[0] + red[1] + red[2] + red[3]) * (1.0f / DIM);
    __syncthreads();

    const float d0 = z0 - mean, d1 = z1 - mean;
    float vq = d0 * d0 + d1 * d1;
    #pragma unroll
    for (int o = 32; o; o >>= 1) vq += __shfl_xor(vq, o);
    if ((t & 63) == 0) red[t >> 6] = vq;
    __syncthreads();
    const float var = (red[0] + red[1] + red[2] + red[3]) * (1.0f / DIM);
    const float rstd = rsqrtf(var + 1e-5f);

    out[base]     = d0 * rstd;
    out[base + 1] = d1 * rstd;
}

// ---------------------------------------------------------------------------
// Staging kernels
// ---------------------------------------------------------------------------
__global__ void build_src_kernel(const float* __restrict__ x,
                                 __hip_bfloat16* __restrict__ src)
{
    int idx = blockIdx.x * 256 + threadIdx.x;   // over S*KDIM_P
    if (idx >= S_LEN * KDIM_P) return;
    int i = idx / KDIM_P, j = idx % KDIM_P;
    float v;
    if (j < 128)       v = x[i * 128 + j];
    else if (j < KDIM) { int e = j - 128; v = (float)(i & ((2 << e) - 1)) / (float)(1 << e); }
    else               v = 0.f;
    src[idx] = __float2bfloat16(v);
}

__global__ void convert_pad_kernel(const float* __restrict__ src,
                                   __hip_bfloat16* __restrict__ dst,
                                   int R, int C, int Cp)
{
    int idx = blockIdx.x * 256 + threadIdx.x;
    if (idx >= R * Cp) return;
    int r = idx / Cp, c = idx % Cp;
    dst[idx] = __float2bfloat16(c < C ? src[(size_t)r * C + c] : 0.f);
}

// conv_w [3][512][512][3] -> wt [3][512][3*512] as [c][k][ci]
__global__ void conv_wt_kernel(const float* __restrict__ w,
                               __hip_bfloat16* __restrict__ wt)
{
    int idx = blockIdx.x * 256 + threadIdx.x;   // over 3*512*1536
    if (idx >= NLAYERS * DIM * CONV_K) return;
    int lc = idx / CONV_K;          // li*512 + c
    int rem = idx % CONV_K;
    int k = rem / DIM, ci = rem % DIM;
    wt[idx] = __float2bfloat16(w[(size_t)lc * CONV_K + ci * 3 + k]);
}

__global__ void zero_pad_rows_kernel(__hip_bfloat16* hp0, __hip_bfloat16* hp1)
{
    const int t = threadIdx.x;  // 512
    const __hip_bfloat16 z = __float2bfloat16(0.f);
    if      (blockIdx.x == 0) hp0[t] = z;
    else if (blockIdx.x == 1) hp0[(size_t)(L_LEN + 1) * DIM + t] = z;
    else if (blockIdx.x == 2) hp1[t] = z;
    else                      hp1[(size_t)(L_LEN + 1) * DIM + t] = z;
}

// ---------------------------------------------------------------------------
extern "C" void kernel_launch(void* const* d_in, const int* in_sizes, int n_in,
                              void* d_out, int out_size, void* d_ws, size_t ws_size,
                              hipStream_t stream)
{
    const float* x        = (const float*)d_in[0];
    const float* residual = (const float*)d_in[1];
    const float* proj_w   = (const float*)d_in[2];
    const float* proj_b   = (const float*)d_in[3];
    const float* q_w      = (const float*)d_in[4];
    const float* k_w      = (const float*)d_in[5];
    const float* v_w      = (const float*)d_in[6];
    const float* in_b     = (const float*)d_in[7];
    const float* out_w    = (const float*)d_in[8];
    const float* out_b    = (const float*)d_in[9];
    const float* conv_w   = (const float*)d_in[10];
    const float* conv_b   = (const float*)d_in[11];
    const float* skip_w   = (const float*)d_in[12];
    const float* skip_b   = (const float*)d_in[13];
    float* out = (float*)d_out;

    char* ws = (char*)d_ws;
    size_t off = 0;
    auto alloc = [&](size_t bytes) { char* p = ws + off; off += (bytes + 255) & ~(size_t)255; return p; };

    __hip_bfloat16* src_b   = (__hip_bfloat16*)alloc((size_t)S_LEN * KDIM_P * 2);
    __hip_bfloat16* projw_b = (__hip_bfloat16*)alloc((size_t)DIM * 5 * KDIM_P * 2);
    __hip_bfloat16* qw_b    = (__hip_bfloat16*)alloc((size_t)DIM * DIM * 2);
    __hip_bfloat16* kw_b    = (__hip_bfloat16*)alloc((size_t)DIM * KDIM_P * 2);
    __hip_bfloat16* vw_b    = (__hip_bfloat16*)alloc((size_t)DIM * KDIM_P * 2);
    __hip_bfloat16* outw_b  = (__hip_bfloat16*)alloc((size_t)DIM * DIM * 2);
    __hip_bfloat16* skipw_b = (__hip_bfloat16*)alloc((size_t)DIM * DIM * 2);
    __hip_bfloat16* convwt  = (__hip_bfloat16*)alloc((size_t)NLAYERS * DIM * CONV_K * 2);
    __hip_bfloat16* tgt_b   = (__hip_bfloat16*)alloc((size_t)L_LEN * DIM * 2);
    __hip_bfloat16* q_b     = (__hip_bfloat16*)alloc((size_t)L_LEN * DIM * 2);
    __hip_bfloat16* k_b     = (__hip_bfloat16*)alloc((size_t)S_LEN * DIM * 2);
    __hip_bfloat16* v_b     = (__hip_bfloat16*)alloc((size_t)S_LEN * DIM * 2);
    __hip_bfloat16* o_b     = (__hip_bfloat16*)alloc((size_t)L_LEN * DIM * 2);
    float*          attn_f  = (float*)alloc((size_t)L_LEN * DIM * 4);   // reused as skip_out
    __hip_bfloat16* hp0     = (__hip_bfloat16*)alloc((size_t)(L_LEN + 2) * DIM * 2);
    __hip_bfloat16* hp1     = (__hip_bfloat16*)alloc((size_t)(L_LEN + 2) * DIM * 2);
    float*          conv_f  = (float*)alloc((size_t)L_LEN * DIM * 4);
    float*          skip_f  = attn_f;  // alias: attn_out dead after LN
    (void)ws_size; (void)n_in; (void)in_sizes; (void)out_size;

    // --- staging ---
    build_src_kernel<<<(S_LEN * KDIM_P + 255) / 256, 256, 0, stream>>>(x, src_b);
    convert_pad_kernel<<<(DIM * 5 * KDIM_P + 255) / 256, 256, 0, stream>>>(proj_w, projw_b, DIM * 5, KDIM, KDIM_P);
    convert_pad_kernel<<<(DIM * DIM + 255) / 256, 256, 0, stream>>>(q_w, qw_b, DIM, DIM, DIM);
    convert_pad_kernel<<<(DIM * KDIM_P + 255) / 256, 256, 0, stream>>>(k_w, kw_b, DIM, KDIM, KDIM_P);
    convert_pad_kernel<<<(DIM * KDIM_P + 255) / 256, 256, 0, stream>>>(v_w, vw_b, DIM, KDIM, KDIM_P);
    convert_pad_kernel<<<(DIM * DIM + 255) / 256, 256, 0, stream>>>(out_w, outw_b, DIM, DIM, DIM);
    convert_pad_kernel<<<(DIM * DIM + 255) / 256, 256, 0, stream>>>(skip_w, skipw_b, DIM, DIM, DIM);
    conv_wt_kernel<<<(NLAYERS * DIM * CONV_K + 255) / 256, 256, 0, stream>>>(conv_w, convwt);
    zero_pad_rows_kernel<<<4, 512, 0, stream>>>(hp0, hp1);

    // --- proj: [2048,160] x [2560,160]^T -> [2048,2560] == tgt [10240,512] ---
    gemm128<false, true><<<dim3(S_LEN / 128, DIM * 5 / 128), 256, 0, stream>>>(
        src_b, KDIM_P, projw_b, KDIM_P, proj_b, tgt_b, nullptr, DIM * 5, KDIM_P);
    // --- q = tgt @ q_w.T + in_b[0:512] ---
    gemm128<false, true><<<dim3(L_LEN / 128, DIM / 128), 256, 0, stream>>>(
        tgt_b, DIM, qw_b, DIM, in_b, q_b, nullptr, DIM, DIM);
    // --- k, v ---
    gemm128<false, true><<<dim3(S_LEN / 128, DIM / 128), 256, 0, stream>>>(
        src_b, KDIM_P, kw_b, KDIM_P, in_b + DIM, k_b, nullptr, DIM, KDIM_P);
    gemm128<false, true><<<dim3(S_LEN / 128, DIM / 128), 256, 0, stream>>>(
        src_b, KDIM_P, vw_b, KDIM_P, in_b + 2 * DIM, v_b, nullptr, DIM, KDIM_P);

    // --- banded attention ---
    attn_kernel<<<L_LEN, 256, 0, stream>>>(q_b, k_b, v_b, o_b);

    // --- out proj -> f32 ---
    gemm128<false, false><<<dim3(L_LEN / 128, DIM / 128), 256, 0, stream>>>(
        o_b, DIM, outw_b, DIM, out_b, nullptr, attn_f, DIM, DIM);

    // --- LN + residual -> hp0 rows 1..L (bf16) ---
    ln_residual_kernel<<<L_LEN, 256, 0, stream>>>(attn_f, residual, hp0);

    // --- skip GEMM (reads cnn_input = hp0+512) -> skip_f ---
    gemm128<false, false><<<dim3(L_LEN / 128, DIM / 128), 256, 0, stream>>>(
        hp0 + DIM, DIM, skipw_b, DIM, skip_b, nullptr, skip_f, DIM, DIM);

    // --- conv stack: sliding-window GEMMs, K=1536, lda=512 ---
    gemm128<true, true><<<dim3(L_LEN / 128, DIM / 128), 256, 0, stream>>>(
        hp0, DIM, convwt, CONV_K, conv_b, hp1 + DIM, nullptr, DIM, CONV_K);
    gemm128<true, true><<<dim3(L_LEN / 128, DIM / 128), 256, 0, stream>>>(
        hp1, DIM, convwt + (size_t)DIM * CONV_K, CONV_K, conv_b + DIM, hp0 + DIM, nullptr, DIM, CONV_K);
    gemm128<true, false><<<dim3(L_LEN / 128, DIM / 128), 256, 0, stream>>>(
        hp0, DIM, convwt + (size_t)2 * DIM * CONV_K, CONV_K, conv_b + 2 * DIM, nullptr, conv_f, DIM, CONV_K);

    // --- final LN ---
    final_ln_kernel<<<L_LEN, 256, 0, stream>>>(conv_f, skip_f, out);
}

// Round 3
// 423.425 us; speedup vs baseline: 1.8826x; 1.1391x over previous
//
#include <hip/hip_runtime.h>
#include <hip/hip_bf16.h>

// ---------------------------------------------------------------------------
// DecoderBlock: proj -> banded MHA -> LN+residual -> 3x conv1d(softplus) -> LN
// S=2048, L=5S=10240, DIM=512, HEADS=4, hd=128, KDIM=136 (pad->160), EXT=64
// GEMMs: m97-style 128x128 tile, LDS staging via global_load_lds(16B).
// Attention: banded one-shot MFMA flash (window <= 30 sources per 16-query
// tile -> single 16x32 score tile, no K-loop).
// ---------------------------------------------------------------------------

#define S_LEN   2048
#define S_PAD   32       // zero pad rows on k_b/v_b for window overrun
#define L_LEN   10240
#define DIM     512
#define KDIM    136
#define KDIM_P  160
#define NPOS    8
#define HEADS   4
#define HDIM    128
#define NLAYERS 3
#define CONV_K  1536

typedef __attribute__((ext_vector_type(8))) short bf16x8;
typedef __attribute__((ext_vector_type(4))) float f32x4;

__device__ __forceinline__ float softplus_f(float x) {
    return x > 20.0f ? x : log1pf(__expf(x));
}

__device__ __forceinline__ void gload_lds16(const __hip_bfloat16* g,
                                            __hip_bfloat16* l) {
    __builtin_amdgcn_global_load_lds(
        (const __attribute__((address_space(1))) void*)g,
        (__attribute__((address_space(3))) void*)l, 16, 0, 0);
}

// ---------------------------------------------------------------------------
// GEMM: C[m,n] = act( sum_k A[m*lda+k] * W[n*ldw+k] + bias[n] )
// Block = 128x128, 4 waves 2x2, each wave 64x64 = 4x4 MFMA tiles.
// ---------------------------------------------------------------------------
template<bool SOFTPLUS, bool OUT_BF16>
__global__ __launch_bounds__(256) void gemm128(
    const __hip_bfloat16* __restrict__ A, int lda,
    const __hip_bfloat16* __restrict__ W, int ldw,
    const float* __restrict__ bias,
    __hip_bfloat16* __restrict__ Cb, float* __restrict__ Cf, int ldc,
    int K)
{
    __shared__ __hip_bfloat16 As[128 * 32];
    __shared__ __hip_bfloat16 Bs[128 * 32];

    const int t = threadIdx.x;
    const int w = t >> 6;
    const int lane = t & 63;
    const int r16 = lane & 15;
    const int quad = lane >> 4;

    const int m0 = blockIdx.x * 128;
    const int n0 = blockIdx.y * 128;
    const int mo = (w >> 1) * 64;
    const int no = (w & 1) * 64;

    const int srow = t >> 2;
    const int scol = (t & 3) * 8;
    const __hip_bfloat16* Ag0 = A + (size_t)(m0 + srow) * lda + scol;
    const __hip_bfloat16* Ag1 = A + (size_t)(m0 + 64 + srow) * lda + scol;
    const __hip_bfloat16* Wg0 = W + (size_t)(n0 + srow) * ldw + scol;
    const __hip_bfloat16* Wg1 = W + (size_t)(n0 + 64 + srow) * ldw + scol;
    __hip_bfloat16* lA0 = &As[(size_t)(w * 64) * 8];
    __hip_bfloat16* lA1 = &As[(size_t)(256 + w * 64) * 8];
    __hip_bfloat16* lB0 = &Bs[(size_t)(w * 64) * 8];
    __hip_bfloat16* lB1 = &Bs[(size_t)(256 + w * 64) * 8];

    f32x4 acc[4][4];
    #pragma unroll
    for (int i = 0; i < 4; ++i)
        #pragma unroll
        for (int j = 0; j < 4; ++j)
            acc[i][j] = (f32x4){0.f, 0.f, 0.f, 0.f};

    for (int k0 = 0; k0 < K; k0 += 32) {
        gload_lds16(Ag0 + k0, lA0);
        gload_lds16(Ag1 + k0, lA1);
        gload_lds16(Wg0 + k0, lB0);
        gload_lds16(Wg1 + k0, lB1);
        __syncthreads();

        bf16x8 af[4], bfr[4];
        #pragma unroll
        for (int i = 0; i < 4; ++i) {
            af[i]  = *(const bf16x8*)&As[(mo + i * 16 + r16) * 32 + quad * 8];
            bfr[i] = *(const bf16x8*)&Bs[(no + i * 16 + r16) * 32 + quad * 8];
        }
        #pragma unroll
        for (int i = 0; i < 4; ++i)
            #pragma unroll
            for (int j = 0; j < 4; ++j)
                acc[i][j] = __builtin_amdgcn_mfma_f32_16x16x32_bf16(
                    af[i], bfr[j], acc[i][j], 0, 0, 0);
        __syncthreads();
    }

    #pragma unroll
    for (int i = 0; i < 4; ++i) {
        const int row_base = m0 + mo + i * 16 + quad * 4;
        #pragma unroll
        for (int j = 0; j < 4; ++j) {
            const int col = n0 + no + j * 16 + r16;
            const float bs = bias[col];
            #pragma unroll
            for (int r = 0; r < 4; ++r) {
                float v = acc[i][j][r] + bs;
                if (SOFTPLUS) v = softplus_f(v);
                const size_t idx = (size_t)(row_base + r) * ldc + col;
                if (OUT_BF16) Cb[idx] = __float2bfloat16(v);
                else          Cf[idx] = v;
            }
        }
    }
}

// ---------------------------------------------------------------------------
// Banded MFMA attention. Block = 16-query tile; wave w = head w.
// Window [i_start, i_start+31] covers all allowed sources (width <= 30).
// QK^T: Q/K frags direct from global (row-major [m|n][k] matches A/B layout).
// Softmax in C-layout; P -> LDS -> A-frag; V window transposed in LDS so
// PV B-frags are ds_read_b128. Exact banded mask applied per element.
// ---------------------------------------------------------------------------
#define VT_STRIDE 40   // u16 stride: 80B rows -> 16B aligned, 2-way-free banks

__global__ __launch_bounds__(256) void attn_mfma_kernel(
    const __hip_bfloat16* __restrict__ qb,   // [L, 512]
    const __hip_bfloat16* __restrict__ kb,   // [S+S_PAD, 512], pad rows zero
    const __hip_bfloat16* __restrict__ vb,   // [S+S_PAD, 512], pad rows zero
    __hip_bfloat16* __restrict__ ob)         // [L, 512]
{
    __shared__ __hip_bfloat16 Vt[HEADS][HDIM * VT_STRIDE];  // [dim][src]
    __shared__ __hip_bfloat16 Ps[HEADS][16 * 32];           // [query][src]

    const int t = threadIdx.x;
    const int h = t >> 6;
    const int lane = t & 63;
    const int r16 = lane & 15;
    const int quad = lane >> 4;
    const int l0 = blockIdx.x * 16;

    int i_start = (l0 - 64) / 5;
    if (i_start < 0) i_start = 0;

    // ---- stage V window transposed: Vt[dim][src] ----
    {
        const int s = lane & 31;
        const int half = lane >> 5;
        const __hip_bfloat16* vrow =
            vb + (size_t)(i_start + s) * DIM + h * HDIM + half * 64;
        short* vt = (short*)Vt[h];
        #pragma unroll
        for (int jj = 0; jj < 8; ++jj) {
            bf16x8 v = *(const bf16x8*)(vrow + jj * 8);
            #pragma unroll
            for (int e = 0; e < 8; ++e)
                vt[(half * 64 + jj * 8 + e) * VT_STRIDE + s] = v[e];
        }
    }

    // ---- QK^T: 16 queries x 32 sources ----
    const short* qg = (const short*)qb + (size_t)(l0 + r16) * DIM + h * HDIM + quad * 8;
    const short* kg0 = (const short*)kb + (size_t)(i_start + r16) * DIM + h * HDIM + quad * 8;
    const short* kg1 = kg0 + 16 * DIM;

    f32x4 c0 = {0.f, 0.f, 0.f, 0.f};
    f32x4 c1 = {0.f, 0.f, 0.f, 0.f};
    #pragma unroll
    for (int kk = 0; kk < 4; ++kk) {
        bf16x8 aq = *(const bf16x8*)(qg + kk * 32);
        bf16x8 b0 = *(const bf16x8*)(kg0 + kk * 32);
        bf16x8 b1 = *(const bf16x8*)(kg1 + kk * 32);
        c0 = __builtin_amdgcn_mfma_f32_16x16x32_bf16(aq, b0, c0, 0, 0, 0);
        c1 = __builtin_amdgcn_mfma_f32_16x16x32_bf16(aq, b1, c1, 0, 0, 0);
    }

    // ---- mask + softmax (rows = queries, cols = sources across 16 lanes) ----
    const float scale = 0.08838834764831845f;   // 1/sqrt(128)
    const int ic0 = i_start + r16;
    const int ic1 = ic0 + 16;
    float recl[4];
    short* ps = (short*)Ps[h];
    #pragma unroll
    for (int r = 0; r < 4; ++r) {
        const int l = l0 + quad * 4 + r;
        const bool a0 = (l >= 5 * ic0 - 64) && (l < 5 * ic0 + 69) && (ic0 < S_LEN);
        const bool a1 = (l >= 5 * ic1 - 64) && (l < 5 * ic1 + 69) && (ic1 < S_LEN);
        float s0 = a0 ? c0[r] * scale : -1e30f;
        float s1 = a1 ? c1[r] * scale : -1e30f;
        float mx = fmaxf(s0, s1);
        #pragma unroll
        for (int o = 8; o; o >>= 1) mx = fmaxf(mx, __shfl_xor(mx, o));
        float e0 = __expf(s0 - mx);
        float e1 = __expf(s1 - mx);
        float sm = e0 + e1;
        #pragma unroll
        for (int o = 8; o; o >>= 1) sm += __shfl_xor(sm, o);
        recl[r] = 1.0f / sm;
        __hip_bfloat16 p0 = __float2bfloat16(e0);
        __hip_bfloat16 p1 = __float2bfloat16(e1);
        ps[(quad * 4 + r) * 32 + r16]      = *(short*)&p0;
        ps[(quad * 4 + r) * 32 + r16 + 16] = *(short*)&p1;
    }

    __syncthreads();

    // ---- PV: P [16x32] x Vt [32 x 128] ----
    bf16x8 ap = *(const bf16x8*)&Ps[h][r16 * 32 + quad * 8];
    #pragma unroll
    for (int nt = 0; nt < 8; ++nt) {
        bf16x8 bv = *(const bf16x8*)&Vt[h][(nt * 16 + r16) * VT_STRIDE + quad * 8];
        f32x4 o = {0.f, 0.f, 0.f, 0.f};
        o = __builtin_amdgcn_mfma_f32_16x16x32_bf16(ap, bv, o, 0, 0, 0);
        #pragma unroll
        for (int r = 0; r < 4; ++r) {
            ob[(size_t)(l0 + quad * 4 + r) * DIM + h * HDIM + nt * 16 + r16] =
                __float2bfloat16(o[r] * recl[r]);
        }
    }
}

// ---------------------------------------------------------------------------
// LayerNorm(attn_out) + residual -> bf16 into padded conv buffer (row r+1)
// ---------------------------------------------------------------------------
__global__ __launch_bounds__(256) void ln_residual_kernel(
    const float* __restrict__ attn_out, const float* __restrict__ residual,
    __hip_bfloat16* __restrict__ hp0)
{
    __shared__ float red[4];
    const int r = blockIdx.x;
    const int t = threadIdx.x;
    const size_t base = (size_t)r * DIM + t * 2;
    float z0 = attn_out[base], z1 = attn_out[base + 1];

    float s = z0 + z1;
    #pragma unroll
    for (int o = 32; o; o >>= 1) s += __shfl_xor(s, o);
    if ((t & 63) == 0) red[t >> 6] = s;
    __syncthreads();
    const float mean = (red[0] + red[1] + red[2] + red[3]) * (1.0f / DIM);
    __syncthreads();

    const float d0 = z0 - mean, d1 = z1 - mean;
    float vq = d0 * d0 + d1 * d1;
    #pragma unroll
    for (int o = 32; o; o >>= 1) vq += __shfl_xor(vq, o);
    if ((t & 63) == 0) red[t >> 6] = vq;
    __syncthreads();
    const float var = (red[0] + red[1] + red[2] + red[3]) * (1.0f / DIM);
    const float rstd = rsqrtf(var + 1e-5f);

    const float y0 = d0 * rstd + residual[base];
    const float y1 = d1 * rstd + residual[base + 1];
    __hip_bfloat16* out = hp0 + (size_t)(r + 1) * DIM + t * 2;
    out[0] = __float2bfloat16(y0);
    out[1] = __float2bfloat16(y1);
}

// ---------------------------------------------------------------------------
// Final: LayerNorm(conv_out + skip_out) -> d_out (f32)
// ---------------------------------------------------------------------------
__global__ __launch_bounds__(256) void final_ln_kernel(
    const float* __restrict__ conv_out, const float* __restrict__ skip_out,
    float* __restrict__ out)
{
    __shared__ float red[4];
    const int r = blockIdx.x;
    const int t = threadIdx.x;
    const size_t base = (size_t)r * DIM + t * 2;
    float z0 = conv_out[base] + skip_out[base];
    float z1 = conv_out[base + 1] + skip_out[base + 1];

    float s = z0 + z1;
    #pragma unroll
    for (int o = 32; o; o >>= 1) s += __shfl_xor(s, o);
    if ((t & 63) == 0) red[t >> 6] = s;
    __syncthreads();
    const float mean = (red[0] + red[1] + red[2] + red[3]) * (1.0f / DIM);
    __syncthreads();

    const float d0 = z0 - mean, d1 = z1 - mean;
    float vq = d0 * d0 + d1 * d1;
    #pragma unroll
    for (int o = 32; o; o >>= 1) vq += __shfl_xor(vq, o);
    if ((t & 63) == 0) red[t >> 6] = vq;
    __syncthreads();
    const float var = (red[0] + red[1] + red[2] + red[3]) * (1.0f / DIM);
    const float rstd = rsqrtf(var + 1e-5f);

    out[base]     = d0 * rstd;
    out[base + 1] = d1 * rstd;
}

// ---------------------------------------------------------------------------
// Staging kernels
// ---------------------------------------------------------------------------
__global__ void build_src_kernel(const float* __restrict__ x,
                                 __hip_bfloat16* __restrict__ src)
{
    int idx = blockIdx.x * 256 + threadIdx.x;
    if (idx >= S_LEN * KDIM_P) return;
    int i = idx / KDIM_P, j = idx % KDIM_P;
    float v;
    if (j < 128)       v = x[i * 128 + j];
    else if (j < KDIM) { int e = j - 128; v = (float)(i & ((2 << e) - 1)) / (float)(1 << e); }
    else               v = 0.f;
    src[idx] = __float2bfloat16(v);
}

__global__ void convert_pad_kernel(const float* __restrict__ src,
                                   __hip_bfloat16* __restrict__ dst,
                                   int R, int C, int Cp)
{
    int idx = blockIdx.x * 256 + threadIdx.x;
    if (idx >= R * Cp) return;
    int r = idx / Cp, c = idx % Cp;
    dst[idx] = __float2bfloat16(c < C ? src[(size_t)r * C + c] : 0.f);
}

// conv_w [3][512][512][3] -> wt [3][512][3*512] as [c][k][ci]
__global__ void conv_wt_kernel(const float* __restrict__ w,
                               __hip_bfloat16* __restrict__ wt)
{
    int idx = blockIdx.x * 256 + threadIdx.x;
    if (idx >= NLAYERS * DIM * CONV_K) return;
    int lc = idx / CONV_K;
    int rem = idx % CONV_K;
    int k = rem / DIM, ci = rem % DIM;
    wt[idx] = __float2bfloat16(w[(size_t)lc * CONV_K + ci * 3 + k]);
}

__global__ void zero_pad_rows_kernel(__hip_bfloat16* hp0, __hip_bfloat16* hp1)
{
    const int t = threadIdx.x;  // 512
    const __hip_bfloat16 z = __float2bfloat16(0.f);
    if      (blockIdx.x == 0) hp0[t] = z;
    else if (blockIdx.x == 1) hp0[(size_t)(L_LEN + 1) * DIM + t] = z;
    else if (blockIdx.x == 2) hp1[t] = z;
    else                      hp1[(size_t)(L_LEN + 1) * DIM + t] = z;
}

// zero the S_PAD overrun rows of k_b and v_b
__global__ void zero_kv_pad_kernel(__hip_bfloat16* k_b, __hip_bfloat16* v_b)
{
    int idx = blockIdx.x * 256 + threadIdx.x;   // over S_PAD*DIM
    if (idx >= S_PAD * DIM) return;
    const __hip_bfloat16 z = __float2bfloat16(0.f);
    k_b[(size_t)S_LEN * DIM + idx] = z;
    v_b[(size_t)S_LEN * DIM + idx] = z;
}

// ---------------------------------------------------------------------------
extern "C" void kernel_launch(void* const* d_in, const int* in_sizes, int n_in,
                              void* d_out, int out_size, void* d_ws, size_t ws_size,
                              hipStream_t stream)
{
    const float* x        = (const float*)d_in[0];
    const float* residual = (const float*)d_in[1];
    const float* proj_w   = (const float*)d_in[2];
    const float* proj_b   = (const float*)d_in[3];
    const float* q_w      = (const float*)d_in[4];
    const float* k_w      = (const float*)d_in[5];
    const float* v_w      = (const float*)d_in[6];
    const float* in_b     = (const float*)d_in[7];
    const float* out_w    = (const float*)d_in[8];
    const float* out_b    = (const float*)d_in[9];
    const float* conv_w   = (const float*)d_in[10];
    const float* conv_b   = (const float*)d_in[11];
    const float* skip_w   = (const float*)d_in[12];
    const float* skip_b   = (const float*)d_in[13];
    float* out = (float*)d_out;

    char* ws = (char*)d_ws;
    size_t off = 0;
    auto alloc = [&](size_t bytes) { char* p = ws + off; off += (bytes + 255) & ~(size_t)255; return p; };

    __hip_bfloat16* src_b   = (__hip_bfloat16*)alloc((size_t)S_LEN * KDIM_P * 2);
    __hip_bfloat16* projw_b = (__hip_bfloat16*)alloc((size_t)DIM * 5 * KDIM_P * 2);
    __hip_bfloat16* qw_b    = (__hip_bfloat16*)alloc((size_t)DIM * DIM * 2);
    __hip_bfloat16* kw_b    = (__hip_bfloat16*)alloc((size_t)DIM * KDIM_P * 2);
    __hip_bfloat16* vw_b    = (__hip_bfloat16*)alloc((size_t)DIM * KDIM_P * 2);
    __hip_bfloat16* outw_b  = (__hip_bfloat16*)alloc((size_t)DIM * DIM * 2);
    __hip_bfloat16* skipw_b = (__hip_bfloat16*)alloc((size_t)DIM * DIM * 2);
    __hip_bfloat16* convwt  = (__hip_bfloat16*)alloc((size_t)NLAYERS * DIM * CONV_K * 2);
    __hip_bfloat16* tgt_b   = (__hip_bfloat16*)alloc((size_t)L_LEN * DIM * 2);
    __hip_bfloat16* q_b     = (__hip_bfloat16*)alloc((size_t)L_LEN * DIM * 2);
    __hip_bfloat16* k_b     = (__hip_bfloat16*)alloc((size_t)(S_LEN + S_PAD) * DIM * 2);
    __hip_bfloat16* v_b     = (__hip_bfloat16*)alloc((size_t)(S_LEN + S_PAD) * DIM * 2);
    __hip_bfloat16* o_b     = (__hip_bfloat16*)alloc((size_t)L_LEN * DIM * 2);
    float*          attn_f  = (float*)alloc((size_t)L_LEN * DIM * 4);
    __hip_bfloat16* hp0     = (__hip_bfloat16*)alloc((size_t)(L_LEN + 2) * DIM * 2);
    __hip_bfloat16* hp1     = (__hip_bfloat16*)alloc((size_t)(L_LEN + 2) * DIM * 2);
    float*          conv_f  = (float*)alloc((size_t)L_LEN * DIM * 4);
    float*          skip_f  = attn_f;
    (void)ws_size; (void)n_in; (void)in_sizes; (void)out_size;

    // --- staging ---
    build_src_kernel<<<(S_LEN * KDIM_P + 255) / 256, 256, 0, stream>>>(x, src_b);
    convert_pad_kernel<<<(DIM * 5 * KDIM_P + 255) / 256, 256, 0, stream>>>(proj_w, projw_b, DIM * 5, KDIM, KDIM_P);
    convert_pad_kernel<<<(DIM * DIM + 255) / 256, 256, 0, stream>>>(q_w, qw_b, DIM, DIM, DIM);
    convert_pad_kernel<<<(DIM * KDIM_P + 255) / 256, 256, 0, stream>>>(k_w, kw_b, DIM, KDIM, KDIM_P);
    convert_pad_kernel<<<(DIM * KDIM_P + 255) / 256, 256, 0, stream>>>(v_w, vw_b, DIM, KDIM, KDIM_P);
    convert_pad_kernel<<<(DIM * DIM + 255) / 256, 256, 0, stream>>>(out_w, outw_b, DIM, DIM, DIM);
    convert_pad_kernel<<<(DIM * DIM + 255) / 256, 256, 0, stream>>>(skip_w, skipw_b, DIM, DIM, DIM);
    conv_wt_kernel<<<(NLAYERS * DIM * CONV_K + 255) / 256, 256, 0, stream>>>(conv_w, convwt);
    zero_pad_rows_kernel<<<4, 512, 0, stream>>>(hp0, hp1);
    zero_kv_pad_kernel<<<(S_PAD * DIM + 255) / 256, 256, 0, stream>>>(k_b, v_b);

    // --- proj ---
    gemm128<false, true><<<dim3(S_LEN / 128, DIM * 5 / 128), 256, 0, stream>>>(
        src_b, KDIM_P, projw_b, KDIM_P, proj_b, tgt_b, nullptr, DIM * 5, KDIM_P);
    // --- q ---
    gemm128<false, true><<<dim3(L_LEN / 128, DIM / 128), 256, 0, stream>>>(
        tgt_b, DIM, qw_b, DIM, in_b, q_b, nullptr, DIM, DIM);
    // --- k, v ---
    gemm128<false, true><<<dim3(S_LEN / 128, DIM / 128), 256, 0, stream>>>(
        src_b, KDIM_P, kw_b, KDIM_P, in_b + DIM, k_b, nullptr, DIM, KDIM_P);
    gemm128<false, true><<<dim3(S_LEN / 128, DIM / 128), 256, 0, stream>>>(
        src_b, KDIM_P, vw_b, KDIM_P, in_b + 2 * DIM, v_b, nullptr, DIM, KDIM_P);

    // --- banded MFMA attention: 640 blocks x (16 queries x 4 heads) ---
    attn_mfma_kernel<<<L_LEN / 16, 256, 0, stream>>>(q_b, k_b, v_b, o_b);

    // --- out proj -> f32 ---
    gemm128<false, false><<<dim3(L_LEN / 128, DIM / 128), 256, 0, stream>>>(
        o_b, DIM, outw_b, DIM, out_b, nullptr, attn_f, DIM, DIM);

    // --- LN + residual -> hp0 rows 1..L (bf16) ---
    ln_residual_kernel<<<L_LEN, 256, 0, stream>>>(attn_f, residual, hp0);

    // --- skip GEMM ---
    gemm128<false, false><<<dim3(L_LEN / 128, DIM / 128), 256, 0, stream>>>(
        hp0 + DIM, DIM, skipw_b, DIM, skip_b, nullptr, skip_f, DIM, DIM);

    // --- conv stack ---
    gemm128<true, true><<<dim3(L_LEN / 128, DIM / 128), 256, 0, stream>>>(
        hp0, DIM, convwt, CONV_K, conv_b, hp1 + DIM, nullptr, DIM, CONV_K);
    gemm128<true, true><<<dim3(L_LEN / 128, DIM / 128), 256, 0, stream>>>(
        hp1, DIM, convwt + (size_t)DIM * CONV_K, CONV_K, conv_b + DIM, hp0 + DIM, nullptr, DIM, CONV_K);
    gemm128<true, false><<<dim3(L_LEN / 128, DIM / 128), 256, 0, stream>>>(
        hp0, DIM, convwt + (size_t)2 * DIM * CONV_K, CONV_K, conv_b + 2 * DIM, nullptr, conv_f, DIM, CONV_K);

    // --- final LN ---
    final_ln_kernel<<<L_LEN, 256, 0, stream>>>(conv_f, skip_f, out);
}

// Round 4
// 371.478 us; speedup vs baseline: 2.1459x; 1.1398x over previous
//
#include <hip/hip_runtime.h>
#include <hip/hip_bf16.h>

// ---------------------------------------------------------------------------
// DecoderBlock: proj -> banded MHA -> LN+residual -> 3x conv1d(softplus) -> LN
// S=2048, L=5S=10240, DIM=512, HEADS=4, hd=128, KDIM=136 (pad->192), EXT=64
// GEMMs: 128x64 block tile (grid 640 for M=10240 -> ~2.5 blocks/CU), BK=32,
// LDS staging via global_load_lds(16B), mfma_f32_16x16x32_bf16.
// Attention: banded one-shot MFMA flash (window <= 30 per 16-query tile).
// ---------------------------------------------------------------------------

#define S_LEN   2048
#define S_PAD   32       // zero pad rows on k_b/v_b for window overrun
#define L_LEN   10240
#define DIM     512
#define KDIM    136
#define KDIM_P  192      // padded to multiple of 32 (and 64)
#define NPOS    8
#define HEADS   4
#define HDIM    128
#define NLAYERS 3
#define CONV_K  1536

typedef __attribute__((ext_vector_type(8))) short bf16x8;
typedef __attribute__((ext_vector_type(4))) float f32x4;

__device__ __forceinline__ float softplus_f(float x) {
    return x > 20.0f ? x : log1pf(__expf(x));
}

__device__ __forceinline__ void gload_lds16(const __hip_bfloat16* g,
                                            __hip_bfloat16* l) {
    __builtin_amdgcn_global_load_lds(
        (const __attribute__((address_space(1))) void*)g,
        (__attribute__((address_space(3))) void*)l, 16, 0, 0);
}

// ---------------------------------------------------------------------------
// GEMM: C[m,n] = act( sum_k A[m*lda+k] * W[n*ldw+k] + bias[n] )
// Block = 128(m) x 64(n), 4 waves 2x2, each wave 64x32 = 4x2 MFMA tiles.
// LDS: As[128][32] 8KB, Bs[64][32] 4KB. Requires M%128==0, N%64==0, K%32==0.
// ---------------------------------------------------------------------------
template<bool SOFTPLUS, bool OUT_BF16>
__global__ __launch_bounds__(256) void gemm_mn(
    const __hip_bfloat16* __restrict__ A, int lda,
    const __hip_bfloat16* __restrict__ W, int ldw,
    const float* __restrict__ bias,
    __hip_bfloat16* __restrict__ Cb, float* __restrict__ Cf, int ldc,
    int K)
{
    __shared__ __hip_bfloat16 As[128 * 32];
    __shared__ __hip_bfloat16 Bs[64 * 32];

    const int t = threadIdx.x;
    const int w = t >> 6;
    const int lane = t & 63;
    const int r16 = lane & 15;
    const int quad = lane >> 4;

    const int m0 = blockIdx.x * 128;
    const int n0 = blockIdx.y * 64;
    const int mo = (w >> 1) * 64;   // wave m-offset: 0 or 64
    const int no = (w & 1) * 32;    // wave n-offset: 0 or 32

    // staging: slot s -> row s>>2, colblock s&3 (8 elems). Wave w, issue i:
    // s = i*256 + w*64 + lane -> row = i*64 + w*16 + (lane>>2), cb = lane&3.
    const int srow = w * 16 + (lane >> 2);
    const int scol = (lane & 3) * 8;
    const __hip_bfloat16* Ag0 = A + (size_t)(m0 + srow) * lda + scol;
    const __hip_bfloat16* Ag1 = A + (size_t)(m0 + 64 + srow) * lda + scol;
    const __hip_bfloat16* Wg  = W + (size_t)(n0 + srow) * ldw + scol;
    __hip_bfloat16* lA0 = &As[(size_t)w * 512];
    __hip_bfloat16* lA1 = &As[2048 + (size_t)w * 512];
    __hip_bfloat16* lB  = &Bs[(size_t)w * 512];

    f32x4 acc[4][2];
    #pragma unroll
    for (int i = 0; i < 4; ++i)
        #pragma unroll
        for (int j = 0; j < 2; ++j)
            acc[i][j] = (f32x4){0.f, 0.f, 0.f, 0.f};

    for (int k0 = 0; k0 < K; k0 += 32) {
        gload_lds16(Ag0 + k0, lA0);
        gload_lds16(Ag1 + k0, lA1);
        gload_lds16(Wg + k0, lB);
        __syncthreads();

        bf16x8 af[4], bfr[2];
        #pragma unroll
        for (int i = 0; i < 4; ++i)
            af[i] = *(const bf16x8*)&As[(mo + i * 16 + r16) * 32 + quad * 8];
        #pragma unroll
        for (int j = 0; j < 2; ++j)
            bfr[j] = *(const bf16x8*)&Bs[(no + j * 16 + r16) * 32 + quad * 8];
        #pragma unroll
        for (int i = 0; i < 4; ++i)
            #pragma unroll
            for (int j = 0; j < 2; ++j)
                acc[i][j] = __builtin_amdgcn_mfma_f32_16x16x32_bf16(
                    af[i], bfr[j], acc[i][j], 0, 0, 0);
        __syncthreads();
    }

    #pragma unroll
    for (int i = 0; i < 4; ++i) {
        const int row_base = m0 + mo + i * 16 + quad * 4;
        #pragma unroll
        for (int j = 0; j < 2; ++j) {
            const int col = n0 + no + j * 16 + r16;
            const float bs = bias[col];
            #pragma unroll
            for (int r = 0; r < 4; ++r) {
                float v = acc[i][j][r] + bs;
                if (SOFTPLUS) v = softplus_f(v);
                const size_t idx = (size_t)(row_base + r) * ldc + col;
                if (OUT_BF16) Cb[idx] = __float2bfloat16(v);
                else          Cf[idx] = v;
            }
        }
    }
}

// ---------------------------------------------------------------------------
// Banded MFMA attention. Block = 16-query tile; wave w = head w.
// ---------------------------------------------------------------------------
#define VT_STRIDE 40   // u16 stride: 80B rows -> 16B aligned

__global__ __launch_bounds__(256) void attn_mfma_kernel(
    const __hip_bfloat16* __restrict__ qb,   // [L, 512]
    const __hip_bfloat16* __restrict__ kb,   // [S+S_PAD, 512], pad rows zero
    const __hip_bfloat16* __restrict__ vb,   // [S+S_PAD, 512], pad rows zero
    __hip_bfloat16* __restrict__ ob)         // [L, 512]
{
    __shared__ __hip_bfloat16 Vt[HEADS][HDIM * VT_STRIDE];  // [dim][src]
    __shared__ __hip_bfloat16 Ps[HEADS][16 * 32];           // [query][src]

    const int t = threadIdx.x;
    const int h = t >> 6;
    const int lane = t & 63;
    const int r16 = lane & 15;
    const int quad = lane >> 4;
    const int l0 = blockIdx.x * 16;

    int i_start = (l0 - 64) / 5;
    if (i_start < 0) i_start = 0;

    // ---- stage V window transposed: Vt[dim][src] ----
    {
        const int s = lane & 31;
        const int half = lane >> 5;
        const __hip_bfloat16* vrow =
            vb + (size_t)(i_start + s) * DIM + h * HDIM + half * 64;
        short* vt = (short*)Vt[h];
        #pragma unroll
        for (int jj = 0; jj < 8; ++jj) {
            bf16x8 v = *(const bf16x8*)(vrow + jj * 8);
            #pragma unroll
            for (int e = 0; e < 8; ++e)
                vt[(half * 64 + jj * 8 + e) * VT_STRIDE + s] = v[e];
        }
    }

    // ---- QK^T: 16 queries x 32 sources ----
    const short* qg = (const short*)qb + (size_t)(l0 + r16) * DIM + h * HDIM + quad * 8;
    const short* kg0 = (const short*)kb + (size_t)(i_start + r16) * DIM + h * HDIM + quad * 8;
    const short* kg1 = kg0 + 16 * DIM;

    f32x4 c0 = {0.f, 0.f, 0.f, 0.f};
    f32x4 c1 = {0.f, 0.f, 0.f, 0.f};
    #pragma unroll
    for (int kk = 0; kk < 4; ++kk) {
        bf16x8 aq = *(const bf16x8*)(qg + kk * 32);
        bf16x8 b0 = *(const bf16x8*)(kg0 + kk * 32);
        bf16x8 b1 = *(const bf16x8*)(kg1 + kk * 32);
        c0 = __builtin_amdgcn_mfma_f32_16x16x32_bf16(aq, b0, c0, 0, 0, 0);
        c1 = __builtin_amdgcn_mfma_f32_16x16x32_bf16(aq, b1, c1, 0, 0, 0);
    }

    // ---- mask + softmax ----
    const float scale = 0.08838834764831845f;   // 1/sqrt(128)
    const int ic0 = i_start + r16;
    const int ic1 = ic0 + 16;
    float recl[4];
    short* ps = (short*)Ps[h];
    #pragma unroll
    for (int r = 0; r < 4; ++r) {
        const int l = l0 + quad * 4 + r;
        const bool a0 = (l >= 5 * ic0 - 64) && (l < 5 * ic0 + 69) && (ic0 < S_LEN);
        const bool a1 = (l >= 5 * ic1 - 64) && (l < 5 * ic1 + 69) && (ic1 < S_LEN);
        float s0 = a0 ? c0[r] * scale : -1e30f;
        float s1 = a1 ? c1[r] * scale : -1e30f;
        float mx = fmaxf(s0, s1);
        #pragma unroll
        for (int o = 8; o; o >>= 1) mx = fmaxf(mx, __shfl_xor(mx, o));
        float e0 = __expf(s0 - mx);
        float e1 = __expf(s1 - mx);
        float sm = e0 + e1;
        #pragma unroll
        for (int o = 8; o; o >>= 1) sm += __shfl_xor(sm, o);
        recl[r] = 1.0f / sm;
        __hip_bfloat16 p0 = __float2bfloat16(e0);
        __hip_bfloat16 p1 = __float2bfloat16(e1);
        ps[(quad * 4 + r) * 32 + r16]      = *(short*)&p0;
        ps[(quad * 4 + r) * 32 + r16 + 16] = *(short*)&p1;
    }

    __syncthreads();

    // ---- PV: P [16x32] x Vt [32 x 128] ----
    bf16x8 ap = *(const bf16x8*)&Ps[h][r16 * 32 + quad * 8];
    #pragma unroll
    for (int nt = 0; nt < 8; ++nt) {
        bf16x8 bv = *(const bf16x8*)&Vt[h][(nt * 16 + r16) * VT_STRIDE + quad * 8];
        f32x4 o = {0.f, 0.f, 0.f, 0.f};
        o = __builtin_amdgcn_mfma_f32_16x16x32_bf16(ap, bv, o, 0, 0, 0);
        #pragma unroll
        for (int r = 0; r < 4; ++r) {
            ob[(size_t)(l0 + quad * 4 + r) * DIM + h * HDIM + nt * 16 + r16] =
                __float2bfloat16(o[r] * recl[r]);
        }
    }
}

// ---------------------------------------------------------------------------
// LayerNorm(attn_out) + residual -> bf16 into padded conv buffer (row r+1)
// ---------------------------------------------------------------------------
__global__ __launch_bounds__(256) void ln_residual_kernel(
    const float* __restrict__ attn_out, const float* __restrict__ residual,
    __hip_bfloat16* __restrict__ hp0)
{
    __shared__ float red[4];
    const int r = blockIdx.x;
    const int t = threadIdx.x;
    const size_t base = (size_t)r * DIM + t * 2;
    float z0 = attn_out[base], z1 = attn_out[base + 1];

    float s = z0 + z1;
    #pragma unroll
    for (int o = 32; o; o >>= 1) s += __shfl_xor(s, o);
    if ((t & 63) == 0) red[t >> 6] = s;
    __syncthreads();
    const float mean = (red[0] + red[1] + red[2] + red[3]) * (1.0f / DIM);
    __syncthreads();

    const float d0 = z0 - mean, d1 = z1 - mean;
    float vq = d0 * d0 + d1 * d1;
    #pragma unroll
    for (int o = 32; o; o >>= 1) vq += __shfl_xor(vq, o);
    if ((t & 63) == 0) red[t >> 6] = vq;
    __syncthreads();
    const float var = (red[0] + red[1] + red[2] + red[3]) * (1.0f / DIM);
    const float rstd = rsqrtf(var + 1e-5f);

    const float y0 = d0 * rstd + residual[base];
    const float y1 = d1 * rstd + residual[base + 1];
    __hip_bfloat16* out = hp0 + (size_t)(r + 1) * DIM + t * 2;
    out[0] = __float2bfloat16(y0);
    out[1] = __float2bfloat16(y1);
}

// ---------------------------------------------------------------------------
// Final: LayerNorm(conv_out + skip_out) -> d_out (f32)
// ---------------------------------------------------------------------------
__global__ __launch_bounds__(256) void final_ln_kernel(
    const float* __restrict__ conv_out, const float* __restrict__ skip_out,
    float* __restrict__ out)
{
    __shared__ float red[4];
    const int r = blockIdx.x;
    const int t = threadIdx.x;
    const size_t base = (size_t)r * DIM + t * 2;
    float z0 = conv_out[base] + skip_out[base];
    float z1 = conv_out[base + 1] + skip_out[base + 1];

    float s = z0 + z1;
    #pragma unroll
    for (int o = 32; o; o >>= 1) s += __shfl_xor(s, o);
    if ((t & 63) == 0) red[t >> 6] = s;
    __syncthreads();
    const float mean = (red[0] + red[1] + red[2] + red[3]) * (1.0f / DIM);
    __syncthreads();

    const float d0 = z0 - mean, d1 = z1 - mean;
    float vq = d0 * d0 + d1 * d1;
    #pragma unroll
    for (int o = 32; o; o >>= 1) vq += __shfl_xor(vq, o);
    if ((t & 63) == 0) red[t >> 6] = vq;
    __syncthreads();
    const float var = (red[0] + red[1] + red[2] + red[3]) * (1.0f / DIM);
    const float rstd = rsqrtf(var + 1e-5f);

    out[base]     = d0 * rstd;
    out[base + 1] = d1 * rstd;
}

// ---------------------------------------------------------------------------
// Staging kernels
// ---------------------------------------------------------------------------
__global__ void build_src_kernel(const float* __restrict__ x,
                                 __hip_bfloat16* __restrict__ src)
{
    int idx = blockIdx.x * 256 + threadIdx.x;
    if (idx >= S_LEN * KDIM_P) return;
    int i = idx / KDIM_P, j = idx % KDIM_P;
    float v;
    if (j < 128)       v = x[i * 128 + j];
    else if (j < KDIM) { int e = j - 128; v = (float)(i & ((2 << e) - 1)) / (float)(1 << e); }
    else               v = 0.f;
    src[idx] = __float2bfloat16(v);
}

__global__ void convert_pad_kernel(const float* __restrict__ src,
                                   __hip_bfloat16* __restrict__ dst,
                                   int R, int C, int Cp)
{
    int idx = blockIdx.x * 256 + threadIdx.x;
    if (idx >= R * Cp) return;
    int r = idx / Cp, c = idx % Cp;
    dst[idx] = __float2bfloat16(c < C ? src[(size_t)r * C + c] : 0.f);
}

// conv_w [3][512][512][3] -> wt [3][512][3*512] as [c][k][ci]
__global__ void conv_wt_kernel(const float* __restrict__ w,
                               __hip_bfloat16* __restrict__ wt)
{
    int idx = blockIdx.x * 256 + threadIdx.x;
    if (idx >= NLAYERS * DIM * CONV_K) return;
    int lc = idx / CONV_K;
    int rem = idx % CONV_K;
    int k = rem / DIM, ci = rem % DIM;
    wt[idx] = __float2bfloat16(w[(size_t)lc * CONV_K + ci * 3 + k]);
}

__global__ void zero_pad_rows_kernel(__hip_bfloat16* hp0, __hip_bfloat16* hp1)
{
    const int t = threadIdx.x;  // 512
    const __hip_bfloat16 z = __float2bfloat16(0.f);
    if      (blockIdx.x == 0) hp0[t] = z;
    else if (blockIdx.x == 1) hp0[(size_t)(L_LEN + 1) * DIM + t] = z;
    else if (blockIdx.x == 2) hp1[t] = z;
    else                      hp1[(size_t)(L_LEN + 1) * DIM + t] = z;
}

// zero the S_PAD overrun rows of k_b and v_b
__global__ void zero_kv_pad_kernel(__hip_bfloat16* k_b, __hip_bfloat16* v_b)
{
    int idx = blockIdx.x * 256 + threadIdx.x;
    if (idx >= S_PAD * DIM) return;
    const __hip_bfloat16 z = __float2bfloat16(0.f);
    k_b[(size_t)S_LEN * DIM + idx] = z;
    v_b[(size_t)S_LEN * DIM + idx] = z;
}

// ---------------------------------------------------------------------------
extern "C" void kernel_launch(void* const* d_in, const int* in_sizes, int n_in,
                              void* d_out, int out_size, void* d_ws, size_t ws_size,
                              hipStream_t stream)
{
    const float* x        = (const float*)d_in[0];
    const float* residual = (const float*)d_in[1];
    const float* proj_w   = (const float*)d_in[2];
    const float* proj_b   = (const float*)d_in[3];
    const float* q_w      = (const float*)d_in[4];
    const float* k_w      = (const float*)d_in[5];
    const float* v_w      = (const float*)d_in[6];
    const float* in_b     = (const float*)d_in[7];
    const float* out_w    = (const float*)d_in[8];
    const float* out_b    = (const float*)d_in[9];
    const float* conv_w   = (const float*)d_in[10];
    const float* conv_b   = (const float*)d_in[11];
    const float* skip_w   = (const float*)d_in[12];
    const float* skip_b   = (const float*)d_in[13];
    float* out = (float*)d_out;

    char* ws = (char*)d_ws;
    size_t off = 0;
    auto alloc = [&](size_t bytes) { char* p = ws + off; off += (bytes + 255) & ~(size_t)255; return p; };

    __hip_bfloat16* src_b   = (__hip_bfloat16*)alloc((size_t)S_LEN * KDIM_P * 2);
    __hip_bfloat16* projw_b = (__hip_bfloat16*)alloc((size_t)DIM * 5 * KDIM_P * 2);
    __hip_bfloat16* qw_b    = (__hip_bfloat16*)alloc((size_t)DIM * DIM * 2);
    __hip_bfloat16* kw_b    = (__hip_bfloat16*)alloc((size_t)DIM * KDIM_P * 2);
    __hip_bfloat16* vw_b    = (__hip_bfloat16*)alloc((size_t)DIM * KDIM_P * 2);
    __hip_bfloat16* outw_b  = (__hip_bfloat16*)alloc((size_t)DIM * DIM * 2);
    __hip_bfloat16* skipw_b = (__hip_bfloat16*)alloc((size_t)DIM * DIM * 2);
    __hip_bfloat16* convwt  = (__hip_bfloat16*)alloc((size_t)NLAYERS * DIM * CONV_K * 2);
    __hip_bfloat16* tgt_b   = (__hip_bfloat16*)alloc((size_t)L_LEN * DIM * 2);
    __hip_bfloat16* q_b     = (__hip_bfloat16*)alloc((size_t)L_LEN * DIM * 2);
    __hip_bfloat16* k_b     = (__hip_bfloat16*)alloc((size_t)(S_LEN + S_PAD) * DIM * 2);
    __hip_bfloat16* v_b     = (__hip_bfloat16*)alloc((size_t)(S_LEN + S_PAD) * DIM * 2);
    __hip_bfloat16* o_b     = (__hip_bfloat16*)alloc((size_t)L_LEN * DIM * 2);
    float*          attn_f  = (float*)alloc((size_t)L_LEN * DIM * 4);
    __hip_bfloat16* hp0     = (__hip_bfloat16*)alloc((size_t)(L_LEN + 2) * DIM * 2);
    __hip_bfloat16* hp1     = (__hip_bfloat16*)alloc((size_t)(L_LEN + 2) * DIM * 2);
    float*          conv_f  = (float*)alloc((size_t)L_LEN * DIM * 4);
    float*          skip_f  = attn_f;
    (void)ws_size; (void)n_in; (void)in_sizes; (void)out_size;

    // --- staging ---
    build_src_kernel<<<(S_LEN * KDIM_P + 255) / 256, 256, 0, stream>>>(x, src_b);
    convert_pad_kernel<<<(DIM * 5 * KDIM_P + 255) / 256, 256, 0, stream>>>(proj_w, projw_b, DIM * 5, KDIM, KDIM_P);
    convert_pad_kernel<<<(DIM * DIM + 255) / 256, 256, 0, stream>>>(q_w, qw_b, DIM, DIM, DIM);
    convert_pad_kernel<<<(DIM * KDIM_P + 255) / 256, 256, 0, stream>>>(k_w, kw_b, DIM, KDIM, KDIM_P);
    convert_pad_kernel<<<(DIM * KDIM_P + 255) / 256, 256, 0, stream>>>(v_w, vw_b, DIM, KDIM, KDIM_P);
    convert_pad_kernel<<<(DIM * DIM + 255) / 256, 256, 0, stream>>>(out_w, outw_b, DIM, DIM, DIM);
    convert_pad_kernel<<<(DIM * DIM + 255) / 256, 256, 0, stream>>>(skip_w, skipw_b, DIM, DIM, DIM);
    conv_wt_kernel<<<(NLAYERS * DIM * CONV_K + 255) / 256, 256, 0, stream>>>(conv_w, convwt);
    zero_pad_rows_kernel<<<4, 512, 0, stream>>>(hp0, hp1);
    zero_kv_pad_kernel<<<(S_PAD * DIM + 255) / 256, 256, 0, stream>>>(k_b, v_b);

    // --- proj: [2048,192] x [2560,192]^T -> [2048,2560] == tgt [10240,512] ---
    gemm_mn<false, true><<<dim3(S_LEN / 128, DIM * 5 / 64), 256, 0, stream>>>(
        src_b, KDIM_P, projw_b, KDIM_P, proj_b, tgt_b, nullptr, DIM * 5, KDIM_P);
    // --- q ---
    gemm_mn<false, true><<<dim3(L_LEN / 128, DIM / 64), 256, 0, stream>>>(
        tgt_b, DIM, qw_b, DIM, in_b, q_b, nullptr, DIM, DIM);
    // --- k, v ---
    gemm_mn<false, true><<<dim3(S_LEN / 128, DIM / 64), 256, 0, stream>>>(
        src_b, KDIM_P, kw_b, KDIM_P, in_b + DIM, k_b, nullptr, DIM, KDIM_P);
    gemm_mn<false, true><<<dim3(S_LEN / 128, DIM / 64), 256, 0, stream>>>(
        src_b, KDIM_P, vw_b, KDIM_P, in_b + 2 * DIM, v_b, nullptr, DIM, KDIM_P);

    // --- banded MFMA attention: 640 blocks x (16 queries x 4 heads) ---
    attn_mfma_kernel<<<L_LEN / 16, 256, 0, stream>>>(q_b, k_b, v_b, o_b);

    // --- out proj -> f32 ---
    gemm_mn<false, false><<<dim3(L_LEN / 128, DIM / 64), 256, 0, stream>>>(
        o_b, DIM, outw_b, DIM, out_b, nullptr, attn_f, DIM, DIM);

    // --- LN + residual -> hp0 rows 1..L (bf16) ---
    ln_residual_kernel<<<L_LEN, 256, 0, stream>>>(attn_f, residual, hp0);

    // --- skip GEMM ---
    gemm_mn<false, false><<<dim3(L_LEN / 128, DIM / 64), 256, 0, stream>>>(
        hp0 + DIM, DIM, skipw_b, DIM, skip_b, nullptr, skip_f, DIM, DIM);

    // --- conv stack: sliding-window GEMMs, K=1536, lda=512 ---
    gemm_mn<true, true><<<dim3(L_LEN / 128, DIM / 64), 256, 0, stream>>>(
        hp0, DIM, convwt, CONV_K, conv_b, hp1 + DIM, nullptr, DIM, CONV_K);
    gemm_mn<true, true><<<dim3(L_LEN / 128, DIM / 64), 256, 0, stream>>>(
        hp1, DIM, convwt + (size_t)DIM * CONV_K, CONV_K, conv_b + DIM, hp0 + DIM, nullptr, DIM, CONV_K);
    gemm_mn<true, false><<<dim3(L_LEN / 128, DIM / 64), 256, 0, stream>>>(
        hp0, DIM, convwt + (size_t)2 * DIM * CONV_K, CONV_K, conv_b + 2 * DIM, nullptr, conv_f, DIM, CONV_K);

    // --- final LN ---
    final_ln_kernel<<<L_LEN, 256, 0, stream>>>(conv_f, skip_f, out);
}

// Round 5
// 368.258 us; speedup vs baseline: 2.1646x; 1.0087x over previous
//
#include <hip/hip_runtime.h>
#include <hip/hip_bf16.h>

// ---------------------------------------------------------------------------
// DecoderBlock: proj -> banded MHA -> LN+residual -> 3x conv1d(softplus) -> LN
// S=2048, L=5S=10240, DIM=512, HEADS=4, hd=128, KDIM=136 (pad->192), EXT=64
// GEMMs: 128x64 block tile, BK=32, DOUBLE-BUFFERED LDS with raw s_barrier +
// fine-grained s_waitcnt vmcnt(3) (prefetch tile k+1 overlaps compute of k).
// Attention: banded one-shot MFMA flash (window <= 30 per 16-query tile).
// ---------------------------------------------------------------------------

#define S_LEN   2048
#define S_PAD   32       // zero pad rows on k_b/v_b for window overrun
#define L_LEN   10240
#define DIM     512
#define KDIM    136
#define KDIM_P  192      // padded to multiple of 32 (and 64)
#define NPOS    8
#define HEADS   4
#define HDIM    128
#define NLAYERS 3
#define CONV_K  1536

typedef __attribute__((ext_vector_type(8))) short bf16x8;
typedef __attribute__((ext_vector_type(4))) float f32x4;

__device__ __forceinline__ float softplus_f(float x) {
    return x > 20.0f ? x : log1pf(__expf(x));
}

__device__ __forceinline__ void gload_lds16(const __hip_bfloat16* g,
                                            __hip_bfloat16* l) {
    __builtin_amdgcn_global_load_lds(
        (const __attribute__((address_space(1))) void*)g,
        (__attribute__((address_space(3))) void*)l, 16, 0, 0);
}

// ---------------------------------------------------------------------------
// GEMM: C[m,n] = act( sum_k A[m*lda+k] * W[n*ldw+k] + bias[n] )
// Block = 128(m) x 64(n), 4 waves 2x2, each wave 64x32 = 4x2 MFMA tiles.
// LDS: double-buffered As[2][128][32] + Bs[2][64][32] = 24 KB.
// Pipeline per K-iter: issue DMA(k+1) -> s_waitcnt vmcnt(3) -> s_barrier ->
// ds_read+MFMA(k) -> lgkmcnt(0) -> s_barrier. No vmcnt(0) drain (m131/m139).
// Requires M%128==0, N%64==0, K%32==0.
// ---------------------------------------------------------------------------
template<bool SOFTPLUS, bool OUT_BF16>
__global__ __launch_bounds__(256) void gemm_mn(
    const __hip_bfloat16* __restrict__ A, int lda,
    const __hip_bfloat16* __restrict__ W, int ldw,
    const float* __restrict__ bias,
    __hip_bfloat16* __restrict__ Cb, float* __restrict__ Cf, int ldc,
    int K)
{
    __shared__ __hip_bfloat16 As[2 * 128 * 32];   // 16 KB
    __shared__ __hip_bfloat16 Bs[2 * 64 * 32];    //  8 KB

    const int t = threadIdx.x;
    const int w = t >> 6;
    const int lane = t & 63;
    const int r16 = lane & 15;
    const int quad = lane >> 4;

    const int m0 = blockIdx.x * 128;
    const int n0 = blockIdx.y * 64;
    const int mo = (w >> 1) * 64;   // wave m-offset: 0 or 64
    const int no = (w & 1) * 32;    // wave n-offset: 0 or 32

    // staging: wave w, issue i covers rows [i*64 + w*16, +16), lane -> (row, 8col)
    const int srow = w * 16 + (lane >> 2);
    const int scol = (lane & 3) * 8;
    const __hip_bfloat16* Ag0 = A + (size_t)(m0 + srow) * lda + scol;
    const __hip_bfloat16* Ag1 = A + (size_t)(m0 + 64 + srow) * lda + scol;
    const __hip_bfloat16* Wg  = W + (size_t)(n0 + srow) * ldw + scol;
    __hip_bfloat16* lA0 = &As[(size_t)w * 512];
    __hip_bfloat16* lA1 = &As[2048 + (size_t)w * 512];
    __hip_bfloat16* lB  = &Bs[(size_t)w * 512];

    f32x4 acc[4][2];
    #pragma unroll
    for (int i = 0; i < 4; ++i)
        #pragma unroll
        for (int j = 0; j < 2; ++j)
            acc[i][j] = (f32x4){0.f, 0.f, 0.f, 0.f};

    const int NK = K >> 5;

    // prologue: tile 0 -> buffer 0
    gload_lds16(Ag0, lA0);
    gload_lds16(Ag1, lA1);
    gload_lds16(Wg,  lB);

    for (int k = 0; k < NK; ++k) {
        const int cur = k & 1;
        if (k + 1 < NK) {
            const int nb = (k + 1) << 5;
            const int nxt = cur ^ 1;
            gload_lds16(Ag0 + nb, lA0 + nxt * 4096);
            gload_lds16(Ag1 + nb, lA1 + nxt * 4096);
            gload_lds16(Wg  + nb, lB  + nxt * 2048);
            asm volatile("s_waitcnt vmcnt(3)" ::: "memory");
        } else {
            asm volatile("s_waitcnt vmcnt(0)" ::: "memory");
        }
        asm volatile("s_barrier" ::: "memory");

        const __hip_bfloat16* Asb = As + cur * 4096;
        const __hip_bfloat16* Bsb = Bs + cur * 2048;
        bf16x8 af[4], bfr[2];
        #pragma unroll
        for (int i = 0; i < 4; ++i)
            af[i] = *(const bf16x8*)&Asb[(mo + i * 16 + r16) * 32 + quad * 8];
        #pragma unroll
        for (int j = 0; j < 2; ++j)
            bfr[j] = *(const bf16x8*)&Bsb[(no + j * 16 + r16) * 32 + quad * 8];
        #pragma unroll
        for (int i = 0; i < 4; ++i)
            #pragma unroll
            for (int j = 0; j < 2; ++j)
                acc[i][j] = __builtin_amdgcn_mfma_f32_16x16x32_bf16(
                    af[i], bfr[j], acc[i][j], 0, 0, 0);

        asm volatile("s_waitcnt lgkmcnt(0)" ::: "memory");
        asm volatile("s_barrier" ::: "memory");
    }

    #pragma unroll
    for (int i = 0; i < 4; ++i) {
        const int row_base = m0 + mo + i * 16 + quad * 4;
        #pragma unroll
        for (int j = 0; j < 2; ++j) {
            const int col = n0 + no + j * 16 + r16;
            const float bs = bias[col];
            #pragma unroll
            for (int r = 0; r < 4; ++r) {
                float v = acc[i][j][r] + bs;
                if (SOFTPLUS) v = softplus_f(v);
                const size_t idx = (size_t)(row_base + r) * ldc + col;
                if (OUT_BF16) Cb[idx] = __float2bfloat16(v);
                else          Cf[idx] = v;
            }
        }
    }
}

// ---------------------------------------------------------------------------
// Banded MFMA attention. Block = 16-query tile; wave w = head w.
// ---------------------------------------------------------------------------
#define VT_STRIDE 40   // u16 stride: 80B rows -> 16B aligned

__global__ __launch_bounds__(256) void attn_mfma_kernel(
    const __hip_bfloat16* __restrict__ qb,   // [L, 512]
    const __hip_bfloat16* __restrict__ kb,   // [S+S_PAD, 512], pad rows zero
    const __hip_bfloat16* __restrict__ vb,   // [S+S_PAD, 512], pad rows zero
    __hip_bfloat16* __restrict__ ob)         // [L, 512]
{
    __shared__ __hip_bfloat16 Vt[HEADS][HDIM * VT_STRIDE];  // [dim][src]
    __shared__ __hip_bfloat16 Ps[HEADS][16 * 32];           // [query][src]

    const int t = threadIdx.x;
    const int h = t >> 6;
    const int lane = t & 63;
    const int r16 = lane & 15;
    const int quad = lane >> 4;
    const int l0 = blockIdx.x * 16;

    int i_start = (l0 - 64) / 5;
    if (i_start < 0) i_start = 0;

    // ---- stage V window transposed: Vt[dim][src] ----
    {
        const int s = lane & 31;
        const int half = lane >> 5;
        const __hip_bfloat16* vrow =
            vb + (size_t)(i_start + s) * DIM + h * HDIM + half * 64;
        short* vt = (short*)Vt[h];
        #pragma unroll
        for (int jj = 0; jj < 8; ++jj) {
            bf16x8 v = *(const bf16x8*)(vrow + jj * 8);
            #pragma unroll
            for (int e = 0; e < 8; ++e)
                vt[(half * 64 + jj * 8 + e) * VT_STRIDE + s] = v[e];
        }
    }

    // ---- QK^T: 16 queries x 32 sources ----
    const short* qg = (const short*)qb + (size_t)(l0 + r16) * DIM + h * HDIM + quad * 8;
    const short* kg0 = (const short*)kb + (size_t)(i_start + r16) * DIM + h * HDIM + quad * 8;
    const short* kg1 = kg0 + 16 * DIM;

    f32x4 c0 = {0.f, 0.f, 0.f, 0.f};
    f32x4 c1 = {0.f, 0.f, 0.f, 0.f};
    #pragma unroll
    for (int kk = 0; kk < 4; ++kk) {
        bf16x8 aq = *(const bf16x8*)(qg + kk * 32);
        bf16x8 b0 = *(const bf16x8*)(kg0 + kk * 32);
        bf16x8 b1 = *(const bf16x8*)(kg1 + kk * 32);
        c0 = __builtin_amdgcn_mfma_f32_16x16x32_bf16(aq, b0, c0, 0, 0, 0);
        c1 = __builtin_amdgcn_mfma_f32_16x16x32_bf16(aq, b1, c1, 0, 0, 0);
    }

    // ---- mask + softmax ----
    const float scale = 0.08838834764831845f;   // 1/sqrt(128)
    const int ic0 = i_start + r16;
    const int ic1 = ic0 + 16;
    float recl[4];
    short* ps = (short*)Ps[h];
    #pragma unroll
    for (int r = 0; r < 4; ++r) {
        const int l = l0 + quad * 4 + r;
        const bool a0 = (l >= 5 * ic0 - 64) && (l < 5 * ic0 + 69) && (ic0 < S_LEN);
        const bool a1 = (l >= 5 * ic1 - 64) && (l < 5 * ic1 + 69) && (ic1 < S_LEN);
        float s0 = a0 ? c0[r] * scale : -1e30f;
        float s1 = a1 ? c1[r] * scale : -1e30f;
        float mx = fmaxf(s0, s1);
        #pragma unroll
        for (int o = 8; o; o >>= 1) mx = fmaxf(mx, __shfl_xor(mx, o));
        float e0 = __expf(s0 - mx);
        float e1 = __expf(s1 - mx);
        float sm = e0 + e1;
        #pragma unroll
        for (int o = 8; o; o >>= 1) sm += __shfl_xor(sm, o);
        recl[r] = 1.0f / sm;
        __hip_bfloat16 p0 = __float2bfloat16(e0);
        __hip_bfloat16 p1 = __float2bfloat16(e1);
        ps[(quad * 4 + r) * 32 + r16]      = *(short*)&p0;
        ps[(quad * 4 + r) * 32 + r16 + 16] = *(short*)&p1;
    }

    __syncthreads();

    // ---- PV: P [16x32] x Vt [32 x 128] ----
    bf16x8 ap = *(const bf16x8*)&Ps[h][r16 * 32 + quad * 8];
    #pragma unroll
    for (int nt = 0; nt < 8; ++nt) {
        bf16x8 bv = *(const bf16x8*)&Vt[h][(nt * 16 + r16) * VT_STRIDE + quad * 8];
        f32x4 o = {0.f, 0.f, 0.f, 0.f};
        o = __builtin_amdgcn_mfma_f32_16x16x32_bf16(ap, bv, o, 0, 0, 0);
        #pragma unroll
        for (int r = 0; r < 4; ++r) {
            ob[(size_t)(l0 + quad * 4 + r) * DIM + h * HDIM + nt * 16 + r16] =
                __float2bfloat16(o[r] * recl[r]);
        }
    }
}

// ---------------------------------------------------------------------------
// LayerNorm(attn_out) + residual -> bf16 into padded conv buffer (row r+1)
// ---------------------------------------------------------------------------
__global__ __launch_bounds__(256) void ln_residual_kernel(
    const float* __restrict__ attn_out, const float* __restrict__ residual,
    __hip_bfloat16* __restrict__ hp0)
{
    __shared__ float red[4];
    const int r = blockIdx.x;
    const int t = threadIdx.x;
    const size_t base = (size_t)r * DIM + t * 2;
    float z0 = attn_out[base], z1 = attn_out[base + 1];

    float s = z0 + z1;
    #pragma unroll
    for (int o = 32; o; o >>= 1) s += __shfl_xor(s, o);
    if ((t & 63) == 0) red[t >> 6] = s;
    __syncthreads();
    const float mean = (red[0] + red[1] + red[2] + red[3]) * (1.0f / DIM);
    __syncthreads();

    const float d0 = z0 - mean, d1 = z1 - mean;
    float vq = d0 * d0 + d1 * d1;
    #pragma unroll
    for (int o = 32; o; o >>= 1) vq += __shfl_xor(vq, o);
    if ((t & 63) == 0) red[t >> 6] = vq;
    __syncthreads();
    const float var = (red[0] + red[1] + red[2] + red[3]) * (1.0f / DIM);
    const float rstd = rsqrtf(var + 1e-5f);

    const float y0 = d0 * rstd + residual[base];
    const float y1 = d1 * rstd + residual[base + 1];
    __hip_bfloat16* out = hp0 + (size_t)(r + 1) * DIM + t * 2;
    out[0] = __float2bfloat16(y0);
    out[1] = __float2bfloat16(y1);
}

// ---------------------------------------------------------------------------
// Final: LayerNorm(conv_out + skip_out) -> d_out (f32)
// ---------------------------------------------------------------------------
__global__ __launch_bounds__(256) void final_ln_kernel(
    const float* __restrict__ conv_out, const float* __restrict__ skip_out,
    float* __restrict__ out)
{
    __shared__ float red[4];
    const int r = blockIdx.x;
    const int t = threadIdx.x;
    const size_t base = (size_t)r * DIM + t * 2;
    float z0 = conv_out[base] + skip_out[base];
    float z1 = conv_out[base + 1] + skip_out[base + 1];

    float s = z0 + z1;
    #pragma unroll
    for (int o = 32; o; o >>= 1) s += __shfl_xor(s, o);
    if ((t & 63) == 0) red[t >> 6] = s;
    __syncthreads();
    const float mean = (red[0] + red[1] + red[2] + red[3]) * (1.0f / DIM);
    __syncthreads();

    const float d0 = z0 - mean, d1 = z1 - mean;
    float vq = d0 * d0 + d1 * d1;
    #pragma unroll
    for (int o = 32; o; o >>= 1) vq += __shfl_xor(vq, o);
    if ((t & 63) == 0) red[t >> 6] = vq;
    __syncthreads();
    const float var = (red[0] + red[1] + red[2] + red[3]) * (1.0f / DIM);
    const float rstd = rsqrtf(var + 1e-5f);

    out[base]     = d0 * rstd;
    out[base + 1] = d1 * rstd;
}

// ---------------------------------------------------------------------------
// Staging kernels
// ---------------------------------------------------------------------------
__global__ void build_src_kernel(const float* __restrict__ x,
                                 __hip_bfloat16* __restrict__ src)
{
    int idx = blockIdx.x * 256 + threadIdx.x;
    if (idx >= S_LEN * KDIM_P) return;
    int i = idx / KDIM_P, j = idx % KDIM_P;
    float v;
    if (j < 128)       v = x[i * 128 + j];
    else if (j < KDIM) { int e = j - 128; v = (float)(i & ((2 << e) - 1)) / (float)(1 << e); }
    else               v = 0.f;
    src[idx] = __float2bfloat16(v);
}

__global__ void convert_pad_kernel(const float* __restrict__ src,
                                   __hip_bfloat16* __restrict__ dst,
                                   int R, int C, int Cp)
{
    int idx = blockIdx.x * 256 + threadIdx.x;
    if (idx >= R * Cp) return;
    int r = idx / Cp, c = idx % Cp;
    dst[idx] = __float2bfloat16(c < C ? src[(size_t)r * C + c] : 0.f);
}

// conv_w [3][512][512][3] -> wt [3][512][3*512] as [c][k][ci]
__global__ void conv_wt_kernel(const float* __restrict__ w,
                               __hip_bfloat16* __restrict__ wt)
{
    int idx = blockIdx.x * 256 + threadIdx.x;
    if (idx >= NLAYERS * DIM * CONV_K) return;
    int lc = idx / CONV_K;
    int rem = idx % CONV_K;
    int k = rem / DIM, ci = rem % DIM;
    wt[idx] = __float2bfloat16(w[(size_t)lc * CONV_K + ci * 3 + k]);
}

__global__ void zero_pad_rows_kernel(__hip_bfloat16* hp0, __hip_bfloat16* hp1)
{
    const int t = threadIdx.x;  // 512
    const __hip_bfloat16 z = __float2bfloat16(0.f);
    if      (blockIdx.x == 0) hp0[t] = z;
    else if (blockIdx.x == 1) hp0[(size_t)(L_LEN + 1) * DIM + t] = z;
    else if (blockIdx.x == 2) hp1[t] = z;
    else                      hp1[(size_t)(L_LEN + 1) * DIM + t] = z;
}

// zero the S_PAD overrun rows of k_b and v_b
__global__ void zero_kv_pad_kernel(__hip_bfloat16* k_b, __hip_bfloat16* v_b)
{
    int idx = blockIdx.x * 256 + threadIdx.x;
    if (idx >= S_PAD * DIM) return;
    const __hip_bfloat16 z = __float2bfloat16(0.f);
    k_b[(size_t)S_LEN * DIM + idx] = z;
    v_b[(size_t)S_LEN * DIM + idx] = z;
}

// ---------------------------------------------------------------------------
extern "C" void kernel_launch(void* const* d_in, const int* in_sizes, int n_in,
                              void* d_out, int out_size, void* d_ws, size_t ws_size,
                              hipStream_t stream)
{
    const float* x        = (const float*)d_in[0];
    const float* residual = (const float*)d_in[1];
    const float* proj_w   = (const float*)d_in[2];
    const float* proj_b   = (const float*)d_in[3];
    const float* q_w      = (const float*)d_in[4];
    const float* k_w      = (const float*)d_in[5];
    const float* v_w      = (const float*)d_in[6];
    const float* in_b     = (const float*)d_in[7];
    const float* out_w    = (const float*)d_in[8];
    const float* out_b    = (const float*)d_in[9];
    const float* conv_w   = (const float*)d_in[10];
    const float* conv_b   = (const float*)d_in[11];
    const float* skip_w   = (const float*)d_in[12];
    const float* skip_b   = (const float*)d_in[13];
    float* out = (float*)d_out;

    char* ws = (char*)d_ws;
    size_t off = 0;
    auto alloc = [&](size_t bytes) { char* p = ws + off; off += (bytes + 255) & ~(size_t)255; return p; };

    __hip_bfloat16* src_b   = (__hip_bfloat16*)alloc((size_t)S_LEN * KDIM_P * 2);
    __hip_bfloat16* projw_b = (__hip_bfloat16*)alloc((size_t)DIM * 5 * KDIM_P * 2);
    __hip_bfloat16* qw_b    = (__hip_bfloat16*)alloc((size_t)DIM * DIM * 2);
    __hip_bfloat16* kw_b    = (__hip_bfloat16*)alloc((size_t)DIM * KDIM_P * 2);
    __hip_bfloat16* vw_b    = (__hip_bfloat16*)alloc((size_t)DIM * KDIM_P * 2);
    __hip_bfloat16* outw_b  = (__hip_bfloat16*)alloc((size_t)DIM * DIM * 2);
    __hip_bfloat16* skipw_b = (__hip_bfloat16*)alloc((size_t)DIM * DIM * 2);
    __hip_bfloat16* convwt  = (__hip_bfloat16*)alloc((size_t)NLAYERS * DIM * CONV_K * 2);
    __hip_bfloat16* tgt_b   = (__hip_bfloat16*)alloc((size_t)L_LEN * DIM * 2);
    __hip_bfloat16* q_b     = (__hip_bfloat16*)alloc((size_t)L_LEN * DIM * 2);
    __hip_bfloat16* k_b     = (__hip_bfloat16*)alloc((size_t)(S_LEN + S_PAD) * DIM * 2);
    __hip_bfloat16* v_b     = (__hip_bfloat16*)alloc((size_t)(S_LEN + S_PAD) * DIM * 2);
    __hip_bfloat16* o_b     = (__hip_bfloat16*)alloc((size_t)L_LEN * DIM * 2);
    float*          attn_f  = (float*)alloc((size_t)L_LEN * DIM * 4);
    __hip_bfloat16* hp0     = (__hip_bfloat16*)alloc((size_t)(L_LEN + 2) * DIM * 2);
    __hip_bfloat16* hp1     = (__hip_bfloat16*)alloc((size_t)(L_LEN + 2) * DIM * 2);
    float*          conv_f  = (float*)alloc((size_t)L_LEN * DIM * 4);
    float*          skip_f  = attn_f;
    (void)ws_size; (void)n_in; (void)in_sizes; (void)out_size;

    // --- staging ---
    build_src_kernel<<<(S_LEN * KDIM_P + 255) / 256, 256, 0, stream>>>(x, src_b);
    convert_pad_kernel<<<(DIM * 5 * KDIM_P + 255) / 256, 256, 0, stream>>>(proj_w, projw_b, DIM * 5, KDIM, KDIM_P);
    convert_pad_kernel<<<(DIM * DIM + 255) / 256, 256, 0, stream>>>(q_w, qw_b, DIM, DIM, DIM);
    convert_pad_kernel<<<(DIM * KDIM_P + 255) / 256, 256, 0, stream>>>(k_w, kw_b, DIM, KDIM, KDIM_P);
    convert_pad_kernel<<<(DIM * KDIM_P + 255) / 256, 256, 0, stream>>>(v_w, vw_b, DIM, KDIM, KDIM_P);
    convert_pad_kernel<<<(DIM * DIM + 255) / 256, 256, 0, stream>>>(out_w, outw_b, DIM, DIM, DIM);
    convert_pad_kernel<<<(DIM * DIM + 255) / 256, 256, 0, stream>>>(skip_w, skipw_b, DIM, DIM, DIM);
    conv_wt_kernel<<<(NLAYERS * DIM * CONV_K + 255) / 256, 256, 0, stream>>>(conv_w, convwt);
    zero_pad_rows_kernel<<<4, 512, 0, stream>>>(hp0, hp1);
    zero_kv_pad_kernel<<<(S_PAD * DIM + 255) / 256, 256, 0, stream>>>(k_b, v_b);

    // --- proj: [2048,192] x [2560,192]^T -> [2048,2560] == tgt [10240,512] ---
    gemm_mn<false, true><<<dim3(S_LEN / 128, DIM * 5 / 64), 256, 0, stream>>>(
        src_b, KDIM_P, projw_b, KDIM_P, proj_b, tgt_b, nullptr, DIM * 5, KDIM_P);
    // --- q ---
    gemm_mn<false, true><<<dim3(L_LEN / 128, DIM / 64), 256, 0, stream>>>(
        tgt_b, DIM, qw_b, DIM, in_b, q_b, nullptr, DIM, DIM);
    // --- k, v ---
    gemm_mn<false, true><<<dim3(S_LEN / 128, DIM / 64), 256, 0, stream>>>(
        src_b, KDIM_P, kw_b, KDIM_P, in_b + DIM, k_b, nullptr, DIM, KDIM_P);
    gemm_mn<false, true><<<dim3(S_LEN / 128, DIM / 64), 256, 0, stream>>>(
        src_b, KDIM_P, vw_b, KDIM_P, in_b + 2 * DIM, v_b, nullptr, DIM, KDIM_P);

    // --- banded MFMA attention: 640 blocks x (16 queries x 4 heads) ---
    attn_mfma_kernel<<<L_LEN / 16, 256, 0, stream>>>(q_b, k_b, v_b, o_b);

    // --- out proj -> f32 ---
    gemm_mn<false, false><<<dim3(L_LEN / 128, DIM / 64), 256, 0, stream>>>(
        o_b, DIM, outw_b, DIM, out_b, nullptr, attn_f, DIM, DIM);

    // --- LN + residual -> hp0 rows 1..L (bf16) ---
    ln_residual_kernel<<<L_LEN, 256, 0, stream>>>(attn_f, residual, hp0);

    // --- skip GEMM ---
    gemm_mn<false, false><<<dim3(L_LEN / 128, DIM / 64), 256, 0, stream>>>(
        hp0 + DIM, DIM, skipw_b, DIM, skip_b, nullptr, skip_f, DIM, DIM);

    // --- conv stack: sliding-window GEMMs, K=1536, lda=512 ---
    gemm_mn<true, true><<<dim3(L_LEN / 128, DIM / 64), 256, 0, stream>>>(
        hp0, DIM, convwt, CONV_K, conv_b, hp1 + DIM, nullptr, DIM, CONV_K);
    gemm_mn<true, true><<<dim3(L_LEN / 128, DIM / 64), 256, 0, stream>>>(
        hp1, DIM, convwt + (size_t)DIM * CONV_K, CONV_K, conv_b + DIM, hp0 + DIM, nullptr, DIM, CONV_K);
    gemm_mn<true, false><<<dim3(L_LEN / 128, DIM / 64), 256, 0, stream>>>(
        hp0, DIM, convwt + (size_t)2 * DIM * CONV_K, CONV_K, conv_b + 2 * DIM, nullptr, conv_f, DIM, CONV_K);

    // --- final LN ---
    final_ln_kernel<<<L_LEN, 256, 0, stream>>>(conv_f, skip_f, out);
}